// Round 16
// baseline (1514.058 us; speedup 1.0000x reference)
//
#include <hip/hip_runtime.h>
#include <cstdint>
#include <cstddef>

// ---------------- types ----------------
typedef __bf16 bf16_t;
typedef _Float16 fp16_t;
typedef bf16_t bf16x8 __attribute__((ext_vector_type(8)));
typedef fp16_t fp16x8 __attribute__((ext_vector_type(8)));
typedef bf16_t bf16x2 __attribute__((ext_vector_type(2)));
typedef fp16_t fp16x2 __attribute__((ext_vector_type(2)));
typedef float  f32x4  __attribute__((ext_vector_type(4)));
typedef float  f32x2  __attribute__((ext_vector_type(2)));

#define GAS __attribute__((address_space(1)))
#define LAS __attribute__((address_space(3)))

__device__ __forceinline__ void g2l16(const void* g, void* l) {
  // async global->LDS, 16B per lane; LDS dest is wave-uniform base + lane*16
  __builtin_amdgcn_global_load_lds((const GAS unsigned int*)g,
                                   (LAS unsigned int*)l, 16, 0, 0);
}

__device__ __forceinline__ f32x4 mfma16(bf16x8 a, bf16x8 b, f32x4 c) {
  return __builtin_amdgcn_mfma_f32_16x16x32_bf16(a, b, c, 0, 0, 0);
}
__device__ __forceinline__ f32x4 mfma16(fp16x8 a, fp16x8 b, f32x4 c) {
  return __builtin_amdgcn_mfma_f32_16x16x32_f16(a, b, c, 0, 0, 0);
}
template <typename T> struct vec8;
template <> struct vec8<bf16_t> { using t = bf16x8; };
template <> struct vec8<fp16_t> { using t = fp16x8; };

// Problem constants
#define HW_  65536      // 256*256
#define NPIX 4096       // 64*64 patch grid
#define KQ   832        // 784 real + pad to 832 (fp16 single-pass), 832 % 64 == 0
#define NPV  1024       // v rows padded to 1024 (784 real)

// ------- decode table: tab[kk] = (c*HW+(ki-1)*256+(kj-1)+257) | ki<<20 | kj<<24 | 1<<28 ----
// kk in [784,1024): 0 (invalid -> value 0). Removes /49,/7 chains from the unfold hot path.
__global__ void build_tab(int* __restrict__ tab) {
  int kk = blockIdx.x * 256 + threadIdx.x;
  int v = 0;
  if (kk < 784) {
    int c = kk / 49, r = kk - c * 49, ki = r / 7, kj = r - ki * 7;
    int off = c * HW_ + (ki - 1) * 256 + (kj - 1) + 257;   // biased, >=0, <2^20
    v = off | (ki << 20) | (kj << 24) | (1 << 28);
  }
  tab[kk] = v;
}

// ------- 1x1 convs, float4-vectorized, 3 block types (z=0: b1<-bo; 1: b2<-dg; 2: b3<-dg) ---
// Per thread: 4 consecutive hw, 16 f32x4 accums (64 VGPR), c-loop unrolled x4 -> 4 float4
// loads (16B/lane, 4KB/wave) in flight. PLAIN launch_bounds(256): round-13's spill came from
// the (256,4) min-waves cap (64-VGPR limit); round-15 showed the compiler allocates freely
// without it. Spill tripwire: WRITE_SIZE must stay ~49MB (round-13 spill showed 665MB).
__global__ __launch_bounds__(256) void conv1x1_3(
    const float* __restrict__ bo, const float* __restrict__ dg,
    const float* __restrict__ gw, const float* __restrict__ gb,
    const float* __restrict__ tw, const float* __restrict__ tb,
    const float* __restrict__ pw, const float* __restrict__ pb,
    fp16_t* __restrict__ b1, bf16_t* __restrict__ b2, fp16_t* __restrict__ b3)
{
  __shared__ float wS[1024], bia[16];
  int tid = threadIdx.x;
  int lb  = blockIdx.y;
  int z   = blockIdx.z;
  const float* w   = (z == 0) ? gw : (z == 1) ? tw : pw;
  const float* bb  = (z == 0) ? gb : (z == 1) ? tb : pb;
  const float* src = ((z == 0) ? bo : dg) + (size_t)lb * 64 * HW_;
  for (int i = tid; i < 1024; i += 256) wS[i] = w[i];
  if (tid < 16) bia[tid] = bb[tid];
  __syncthreads();

  size_t hw = ((size_t)blockIdx.x * 256 + tid) * 4;
  f32x4 acc[16];
#pragma unroll
  for (int o = 0; o < 16; ++o) {
    float bv = bia[o];
    acc[o] = f32x4{bv, bv, bv, bv};
  }
  for (int c = 0; c < 64; c += 4) {
    float4 v0 = *(const float4*)(src + (size_t)(c + 0) * HW_ + hw);
    float4 v1 = *(const float4*)(src + (size_t)(c + 1) * HW_ + hw);
    float4 v2 = *(const float4*)(src + (size_t)(c + 2) * HW_ + hw);
    float4 v3 = *(const float4*)(src + (size_t)(c + 3) * HW_ + hw);
#pragma unroll
    for (int o = 0; o < 16; ++o) {
      float w0 = wS[o * 64 + c + 0];
      float w1 = wS[o * 64 + c + 1];
      float w2 = wS[o * 64 + c + 2];
      float w3 = wS[o * 64 + c + 3];
      acc[o][0] = fmaf(w0, v0.x, acc[o][0]);
      acc[o][1] = fmaf(w0, v0.y, acc[o][1]);
      acc[o][2] = fmaf(w0, v0.z, acc[o][2]);
      acc[o][3] = fmaf(w0, v0.w, acc[o][3]);
      acc[o][0] = fmaf(w1, v1.x, acc[o][0]);
      acc[o][1] = fmaf(w1, v1.y, acc[o][1]);
      acc[o][2] = fmaf(w1, v1.z, acc[o][2]);
      acc[o][3] = fmaf(w1, v1.w, acc[o][3]);
      acc[o][0] = fmaf(w2, v2.x, acc[o][0]);
      acc[o][1] = fmaf(w2, v2.y, acc[o][1]);
      acc[o][2] = fmaf(w2, v2.z, acc[o][2]);
      acc[o][3] = fmaf(w2, v2.w, acc[o][3]);
      acc[o][0] = fmaf(w3, v3.x, acc[o][0]);
      acc[o][1] = fmaf(w3, v3.y, acc[o][1]);
      acc[o][2] = fmaf(w3, v3.z, acc[o][2]);
      acc[o][3] = fmaf(w3, v3.w, acc[o][3]);
    }
  }
  if (z == 1) {
    bf16_t* dst = b2 + (size_t)lb * 16 * HW_;
#pragma unroll
    for (int o = 0; o < 16; ++o) {
      union { bf16_t h[4]; ushort4 u4; } pk;
      pk.h[0] = (bf16_t)acc[o][0];
      pk.h[1] = (bf16_t)acc[o][1];
      pk.h[2] = (bf16_t)acc[o][2];
      pk.h[3] = (bf16_t)acc[o][3];
      *(ushort4*)(dst + (size_t)o * HW_ + hw) = pk.u4;
    }
  } else {
    fp16_t* dst = ((z == 0) ? b1 : b3) + (size_t)lb * 16 * HW_;
#pragma unroll
    for (int o = 0; o < 16; ++o) {
      union { fp16_t h[4]; ushort4 u4; } pk;
      pk.h[0] = (fp16_t)acc[o][0];
      pk.h[1] = (fp16_t)acc[o][1];
      pk.h[2] = (fp16_t)acc[o][2];
      pk.h[3] = (fp16_t)acc[o][3];
      *(ushort4*)(dst + (size_t)o * HW_ + hw) = pk.u4;
    }
  }
}

// ------- unfold q & k, table-driven, 8 gathers in flight ----------------------------------
// thread: kk in {tid+256u}, patches {i0, i0+2048}; grid (1, 2048, 2G), z = lb*2 + sel.
__global__ __launch_bounds__(256) void unfold_qk(const fp16_t* __restrict__ b1,
                                                 const fp16_t* __restrict__ b3,
                                                 fp16_t* __restrict__ qb,
                                                 fp16_t* __restrict__ kb,
                                                 const int* __restrict__ tab)
{
  int tid = threadIdx.x;
  int lb = blockIdx.z >> 1, sel = blockIdx.z & 1;
  const fp16_t* src = (sel ? b3 : b1) + (size_t)lb * 16 * HW_;
  fp16_t* dst       = (sel ? kb : qb) + (size_t)lb * NPIX * KQ;
  int i0 = blockIdx.y, i1 = i0 + 2048;
  int oy0 = i0 >> 6, ox0 = i0 & 63;
  int oy1 = i1 >> 6, ox1 = i1 & 63;
  int pb0 = oy0 * 1024 + ox0 * 4;
  int pb1 = oy1 * 1024 + ox1 * 4;
  int t[4];
#pragma unroll
  for (int u = 0; u < 4; ++u) t[u] = tab[tid + u * 256];
  fp16_t v0[4], v1[4];
#pragma unroll
  for (int u = 0; u < 4; ++u) {
    int off = (t[u] & 0xFFFFF) - 257;
    int ki  = (t[u] >> 20) & 15;
    int kj  = (t[u] >> 24) & 15;
    int vld = t[u] >> 28;
    int y0 = oy0 * 4 + ki - 1, x0 = ox0 * 4 + kj - 1;
    int y1 = oy1 * 4 + ki - 1, x1 = ox1 * 4 + kj - 1;
    v0[u] = (vld && (unsigned)y0 < 256u && (unsigned)x0 < 256u)
            ? src[pb0 + off] : (fp16_t)0.f;
    v1[u] = (vld && (unsigned)y1 < 256u && (unsigned)x1 < 256u)
            ? src[pb1 + off] : (fp16_t)0.f;
  }
#pragma unroll
  for (int u = 0; u < 4; ++u) {
    int kk = tid + u * 256;
    if (kk < KQ) {
      dst[(size_t)i0 * KQ + kk] = v0[u];
      dst[(size_t)i1 * KQ + kk] = v1[u];
    }
  }
}

// ------- v unfold, table-driven (wave-uniform row decode), 4 gathers in flight -------------
// grid (4, NPV, G): p = blockIdx.y, j = blockIdx.x*1024 + tid + 256u.
__global__ __launch_bounds__(256) void unfold_v(const bf16_t* __restrict__ src,
                                                bf16_t* __restrict__ vb,
                                                const int* __restrict__ tab)
{
  int tid = threadIdx.x;
  int p  = blockIdx.y;
  int lb = blockIdx.z;
  src += (size_t)lb * 16 * HW_;
  vb  += (size_t)lb * NPV * 4096;
  int t = tab[p];                       // wave-uniform -> scalar load
  int off = (t & 0xFFFFF) - 257;
  int ki  = (t >> 20) & 15;
  int kj  = (t >> 24) & 15;
  int vld = t >> 28;
  int jb = blockIdx.x * 1024 + tid;
  bf16_t v[4];
#pragma unroll
  for (int u = 0; u < 4; ++u) {
    int j = jb + u * 256;
    int oy = j >> 6, ox = j & 63;
    int y = oy * 4 + ki - 1, x = ox * 4 + kj - 1;
    v[u] = (vld && (unsigned)y < 256u && (unsigned)x < 256u)
           ? src[oy * 1024 + ox * 4 + off] : (bf16_t)0.f;
  }
#pragma unroll
  for (int u = 0; u < 4; ++u)
    vb[(size_t)p * 4096 + jb + u * 256] = v[u];
}

// ---------------- 256x256-tile GEMM, 8-phase schedule: C = alpha*A(MxK)*B(NxK)^T -----------
// (round-6 known-good) 8 waves (2M x 4N), BK=64 in two K-halves of 32. LDS = ring of 8 x
// 16KiB half-slots. Tile t occupies slots (t&1)*4 + {0:Ak0, 1:Bk0, 2:Ak1, 3:Bk1}.
// Per phase: {ds_read frags -> stage 1 half -> barrier -> lgkmcnt(0) -> 16 MFMA -> barrier};
// boundary vmcnt(6) per tile (vmcnt(0) at t==T-2). REQUIRES: K % 64 == 0, T = K/64 >= 3.
// OT = output element type (float or bf16_t) — bf16 halves epilogue/partial traffic.
template <typename T, typename OT>
__global__ __launch_bounds__(512, 2) void gemm256(
    const T* __restrict__ A, int lda,
    const T* __restrict__ B, int ldb,
    OT* __restrict__ C, int ldc,
    int nbn, int bps, size_t csplit, int K, int kofs, float alpha)
{
  using v8t = typename vec8<T>::t;
  __shared__ __align__(16) T lds[8][8192];   // 8 half-slots x 16 KiB = 128 KiB

  int nwg = gridDim.x, wg = blockIdx.x;
  int swz = ((nwg & 7) == 0) ? ((wg & 7) * (nwg >> 3) + (wg >> 3)) : wg;
  int s   = swz / bps;
  int rem = swz - s * bps;
  int bm  = rem / nbn, bn = rem - bm * nbn;
  A += (size_t)s * kofs;
  B += (size_t)s * kofs;
  C += (size_t)s * csplit;

  int tid  = threadIdx.x;
  int lane = tid & 63;
  int wid  = tid >> 6;
  int wr   = wid >> 2, wc = wid & 3;        // wave -> 128-row x 64-col output block
  int l16  = lane & 15;

  // staging: instr u stages cell u*512+tid; cell = kb*256+row, kb = u*2+(tid>>8),
  // row = tid&255; global k-elem offset = half_kofs + kb*8.
  const T* gA = A + (size_t)(bm * 256 + (tid & 255)) * lda + (tid >> 8) * 8;
  const T* gB = B + (size_t)(bn * 256 + (tid & 255)) * ldb + (tid >> 8) * 8;

#define STAGE(gsrc, koffe, slot) {                                   \
    const T* _s = (gsrc) + (koffe);                                  \
    g2l16(_s,      &lds[slot][(size_t)tid * 8]);                     \
    g2l16(_s + 16, &lds[slot][(size_t)(512 + tid) * 8]); }

  // fragment read offsets (elements) within a half-slot: cell = (lane>>4)*256 + row
  int aoff = ((lane >> 4) * 256 + wr * 128 + l16) * 8;
  int boff = ((lane >> 4) * 256 + wc * 64 + l16) * 8;

  f32x4 acc[8][4];
#pragma unroll
  for (int f = 0; f < 8; ++f)
#pragma unroll
    for (int q = 0; q < 4; ++q) acc[f][q] = f32x4{0.f, 0.f, 0.f, 0.f};

  int T_ = K >> 6;   // BK = 64

  // prologue: 7 halves in steady-state order
  STAGE(gB, 0, 1)        // Bk0(0)
  STAGE(gA, 0, 0)        // Ak0(0)
  STAGE(gB, 32, 3)       // Bk1(0)
  STAGE(gA, 32, 2)       // Ak1(0)
  STAGE(gB, 64, 5)       // Bk0(1)
  STAGE(gA, 64, 4)       // Ak0(1)
  STAGE(gB, 96, 7)       // Bk1(1)
  asm volatile("s_waitcnt vmcnt(6)" ::: "memory");   // tile 0 fully resident
  __builtin_amdgcn_s_barrier();

  for (int t = 0; t < T_; ++t) {
    int pi = (t & 1) * 4;          // current tile's slot base
    int po = ((t + 1) & 1) * 4;    // other parity
    const T* sAk0 = &lds[pi + 0][0];
    const T* sBk0 = &lds[pi + 1][0];
    const T* sAk1 = &lds[pi + 2][0];
    const T* sBk1 = &lds[pi + 3][0];
    v8t bg[4], af[4];

    // ---- phase 0: read B(ks0) + A(ks0, rf0-3) | stage Ak1(t+1) | MFMA q0 ----
#pragma unroll
    for (int q = 0; q < 4; ++q) bg[q] = *(const v8t*)(sBk0 + boff + q * 128);
#pragma unroll
    for (int f = 0; f < 4; ++f) af[f] = *(const v8t*)(sAk0 + aoff + f * 128);
    if (t + 1 < T_) STAGE(gA, (t + 1) * 64 + 32, po + 2)
    __builtin_amdgcn_s_barrier();
    asm volatile("s_waitcnt lgkmcnt(0)" ::: "memory");
    __builtin_amdgcn_sched_barrier(0);
    __builtin_amdgcn_s_setprio(1);
#pragma unroll
    for (int f = 0; f < 4; ++f)
#pragma unroll
      for (int q = 0; q < 4; ++q)
        acc[f][q] = mfma16(af[f], bg[q], acc[f][q]);
    __builtin_amdgcn_s_setprio(0);
    __builtin_amdgcn_s_barrier();

    // ---- phase 1: read A(ks0, rf4-7) | stage Bk0(t+2) | MFMA q1 ----
#pragma unroll
    for (int f = 0; f < 4; ++f) af[f] = *(const v8t*)(sAk0 + aoff + 512 + f * 128);
    if (t + 2 < T_) STAGE(gB, (t + 2) * 64, pi + 1)
    __builtin_amdgcn_s_barrier();
    asm volatile("s_waitcnt lgkmcnt(0)" ::: "memory");
    __builtin_amdgcn_sched_barrier(0);
    __builtin_amdgcn_s_setprio(1);
#pragma unroll
    for (int f = 0; f < 4; ++f)
#pragma unroll
      for (int q = 0; q < 4; ++q)
        acc[4 + f][q] = mfma16(af[f], bg[q], acc[4 + f][q]);
    __builtin_amdgcn_s_setprio(0);
    __builtin_amdgcn_s_barrier();

    // ---- phase 2: read B(ks1) + A(ks1, rf0-3) | stage Ak0(t+2) | MFMA q2 ----
#pragma unroll
    for (int q = 0; q < 4; ++q) bg[q] = *(const v8t*)(sBk1 + boff + q * 128);
#pragma unroll
    for (int f = 0; f < 4; ++f) af[f] = *(const v8t*)(sAk1 + aoff + f * 128);
    if (t + 2 < T_) STAGE(gA, (t + 2) * 64, pi + 0)
    __builtin_amdgcn_s_barrier();
    asm volatile("s_waitcnt lgkmcnt(0)" ::: "memory");
    __builtin_amdgcn_sched_barrier(0);
    __builtin_amdgcn_s_setprio(1);
#pragma unroll
    for (int f = 0; f < 4; ++f)
#pragma unroll
      for (int q = 0; q < 4; ++q)
        acc[f][q] = mfma16(af[f], bg[q], acc[f][q]);
    __builtin_amdgcn_s_setprio(0);
    __builtin_amdgcn_s_barrier();

    // ---- phase 3: read A(ks1, rf4-7) | stage Bk1(t+2) | MFMA q3 | boundary vmcnt ----
#pragma unroll
    for (int f = 0; f < 4; ++f) af[f] = *(const v8t*)(sAk1 + aoff + 512 + f * 128);
    if (t + 2 < T_) STAGE(gB, (t + 2) * 64 + 32, pi + 3)
    __builtin_amdgcn_s_barrier();
    asm volatile("s_waitcnt lgkmcnt(0)" ::: "memory");
    __builtin_amdgcn_sched_barrier(0);
    __builtin_amdgcn_s_setprio(1);
#pragma unroll
    for (int f = 0; f < 4; ++f)
#pragma unroll
      for (int q = 0; q < 4; ++q)
        acc[4 + f][q] = mfma16(af[f], bg[q], acc[4 + f][q]);
    __builtin_amdgcn_s_setprio(0);
    if (t < T_ - 2)       { asm volatile("s_waitcnt vmcnt(6)" ::: "memory"); }
    else if (t == T_ - 2) { asm volatile("s_waitcnt vmcnt(0)" ::: "memory"); }
    __builtin_amdgcn_s_barrier();
  }
#undef STAGE

  // C/D layout: col = lane&15, row = (lane>>4)*4 + reg ; frag rows = wr*128 + F*16
  int r0 = bm * 256 + wr * 128 + (lane >> 4) * 4;
  int c0 = bn * 256 + wc * 64 + l16;
#pragma unroll
  for (int f = 0; f < 8; ++f)
#pragma unroll
    for (int q = 0; q < 4; ++q) {
      OT* cp = C + (size_t)(r0 + f * 16) * ldc + c0 + q * 16;
#pragma unroll
      for (int r = 0; r < 4; ++r) cp[(size_t)r * ldc] = (OT)(alpha * acc[f][q][r]);
    }
}

// ---------------- fused row softmax: att = softmax(score) as bf16 ----------------
__global__ __launch_bounds__(256) void softmax_rows(const float* __restrict__ S,
                                                    bf16_t* __restrict__ Att)
{
  int row = blockIdx.x;
  int tid = threadIdx.x;
  int lane = tid & 63, wid = tid >> 6;
  const float4* Sp = (const float4*)(S + (size_t)row * 4096);
  float4 vv[4];
  float m = -3.4e38f;
#pragma unroll
  for (int u = 0; u < 4; ++u) {
    vv[u] = Sp[u * 256 + tid];
    m = fmaxf(m, fmaxf(fmaxf(vv[u].x, vv[u].y), fmaxf(vv[u].z, vv[u].w)));
  }
#pragma unroll
  for (int off = 32; off; off >>= 1) m = fmaxf(m, __shfl_xor(m, off));
  __shared__ float redm[4], reds[4];
  if (lane == 0) redm[wid] = m;
  __syncthreads();
  m = fmaxf(fmaxf(redm[0], redm[1]), fmaxf(redm[2], redm[3]));
  float ssum = 0.f;
#pragma unroll
  for (int u = 0; u < 4; ++u) {
    vv[u].x = __expf(vv[u].x - m); vv[u].y = __expf(vv[u].y - m);
    vv[u].z = __expf(vv[u].z - m); vv[u].w = __expf(vv[u].w - m);
    ssum += vv[u].x + vv[u].y + vv[u].z + vv[u].w;
  }
#pragma unroll
  for (int off = 32; off; off >>= 1) ssum += __shfl_xor(ssum, off);
  if (lane == 0) reds[wid] = ssum;
  __syncthreads();
  float inv = 1.0f / (reds[0] + reds[1] + reds[2] + reds[3]);
  ushort4* Ap = (ushort4*)(Att + (size_t)row * 4096);
#pragma unroll
  for (int u = 0; u < 4; ++u) {
    union { bf16_t b[4]; ushort4 q; } pk;
    pk.b[0] = (bf16_t)(vv[u].x * inv);
    pk.b[1] = (bf16_t)(vv[u].y * inv);
    pk.b[2] = (bf16_t)(vv[u].z * inv);
    pk.b[3] = (bf16_t)(vv[u].w * inv);
    Ap[u * 256 + tid] = pk.q;
  }
}

// ---------------- split-K reduce: amv = sum_s part[s] (bf16 partials, coalesced) -----------
__global__ __launch_bounds__(256) void reduce4(const bf16_t* __restrict__ part,
                                               float* __restrict__ amv)
{
  size_t i = ((size_t)blockIdx.x * 256 + threadIdx.x) * 8;   // over 4096*1024 elems
  const size_t S = (size_t)4096 * 1024;
  bf16x8 a = *(const bf16x8*)(part + i);
  bf16x8 b = *(const bf16x8*)(part + i + S);
  bf16x8 c = *(const bf16x8*)(part + i + 2 * S);
  bf16x8 d = *(const bf16x8*)(part + i + 3 * S);
  float o[8];
#pragma unroll
  for (int j = 0; j < 8; ++j)
    o[j] = (float)a[j] + (float)b[j] + (float)c[j] + (float)d[j];
  float4* op = (float4*)(amv + i);
  op[0] = float4{o[0], o[1], o[2], o[3]};
  op[1] = float4{o[4], o[5], o[6], o[7]};
}

// ---------------- fold (k=7,s=4,pad=3) + mask normalize -> zi[16][256][256] ----------------
__global__ __launch_bounds__(256) void fold_norm(const float* __restrict__ amv,
                                                 float* __restrict__ zi)
{
  int idx = blockIdx.x * 256 + threadIdx.x;   // c*65536 + h*256 + w
  int c = idx >> 16;
  int h = (idx >> 8) & 255;
  int w = idx & 255;
  int t = h + 3, u = w + 3;
  int oy0 = (t - 3) >> 2, oy1 = min(63, t >> 2);
  int ox0 = (u - 3) >> 2, ox1 = min(63, u >> 2);
  float sum = 0.f;
  for (int oy = oy0; oy <= oy1; ++oy) {
    int ki = t - oy * 4;
    for (int ox = ox0; ox <= ox1; ++ox) {
      int kj = u - ox * 4;
      sum += amv[(size_t)(oy * 64 + ox) * NPV + c * 49 + ki * 7 + kj];
    }
  }
  int cnt = (oy1 - oy0 + 1) * (ox1 - ox0 + 1);
  zi[idx] = sum / (float)cnt;
}

// ---------------- final: out = bo + w_w*zi + w_b ----------------
__global__ __launch_bounds__(256) void out_conv(const float* __restrict__ zi,
                                                const float* __restrict__ bo,
                                                const float* __restrict__ ww,
                                                const float* __restrict__ wb,
                                                float* __restrict__ outb)
{
  __shared__ float wws[1024], wbs[64];
  int tid = threadIdx.x;
  for (int i = tid; i < 1024; i += 256) wws[i] = ww[i];
  if (tid < 64) wbs[tid] = wb[tid];
  __syncthreads();
  int hw = blockIdx.x * 256 + tid;
  float z[16];
#pragma unroll
  for (int c = 0; c < 16; ++c) z[c] = zi[(size_t)c * HW_ + hw];
  for (int o = 0; o < 64; ++o) {
    float a = wbs[o];
#pragma unroll
    for (int c = 0; c < 16; ++c) a = fmaf(wws[o * 16 + c], z[c], a);
    outb[(size_t)o * HW_ + hw] = bo[(size_t)o * HW_ + hw] + a;
  }
}

// ---------------- host orchestration ----------------
static inline size_t alup(size_t x) { return (x + 255) & ~(size_t)255; }

extern "C" void kernel_launch(void* const* d_in, const int* in_sizes, int n_in,
                              void* d_out, int out_size, void* d_ws, size_t ws_size,
                              hipStream_t stream) {
  const float* s   = (const float*)d_in[0];
  const float* g   = (const float*)d_in[1];
  const float* g_w = (const float*)d_in[2];
  const float* g_b = (const float*)d_in[3];
  const float* t_w = (const float*)d_in[4];
  const float* t_b = (const float*)d_in[5];
  const float* p_w = (const float*)d_in[6];
  const float* p_b = (const float*)d_in[7];
  const float* w_w = (const float*)d_in[8];
  const float* w_b = (const float*)d_in[9];
  float* out = (float*)d_out;

  // Per-G front-buffer sizes + fixed middle/back sizes
  const size_t szB1 = (size_t)16 * HW_ * 2;          // fp16/bf16 conv outs (per batch)
  const size_t szQK = (size_t)NPIX * KQ * 2;         // per batch
  const size_t szV  = (size_t)NPV * 4096 * 2;        // per batch
  const size_t szSc = (size_t)NPIX * NPIX * 4;       // score (f32), part (bf16) aliases
  const size_t szAtt = (size_t)NPIX * NPIX * 2;
  const size_t szZi  = (size_t)16 * HW_ * 4;
  const size_t szAmv = (size_t)NPIX * NPV * 4;
  const size_t szTab = (size_t)1024 * 4;

  // choose largest G in {8,4,2,1} whose layout fits ws_size (deterministic)
  int G = 1;
  for (int cand = 8; cand >= 1; cand >>= 1) {
    size_t need = alup(szB1) * 3 * cand + alup(szQK) * 2 * cand + alup(szV) * cand
                + alup(szSc) + alup(szAtt) + alup(szZi) + alup(szAmv) + alup(szTab);
    if (need <= ws_size) { G = cand; break; }
  }

  uint8_t* wp = (uint8_t*)d_ws;
  fp16_t* b1    = (fp16_t*)wp; wp += alup(szB1) * G;
  bf16_t* b2    = (bf16_t*)wp; wp += alup(szB1) * G;
  fp16_t* b3    = (fp16_t*)wp; wp += alup(szB1) * G;
  fp16_t* qbuf  = (fp16_t*)wp; wp += alup(szQK) * G;
  fp16_t* kbuf  = (fp16_t*)wp; wp += alup(szQK) * G;
  bf16_t* vbufp = (bf16_t*)wp; wp += alup(szV) * G;
  float*  score = (float*)wp;  wp += alup(szSc);
  bf16_t* att   = (bf16_t*)wp; wp += alup(szAtt);
  float*  zi    = (float*)wp;  wp += alup(szZi);
  float*  amv   = (float*)wp;  wp += alup(szAmv);
  int*    tab   = (int*)wp;    wp += alup(szTab);
  bf16_t* part  = (bf16_t*)score;   // score dead after softmax; 4*4096*1024 bf16 = 32MB

  build_tab<<<dim3(4), dim3(256), 0, stream>>>(tab);

  for (int g0 = 0; g0 < 8; g0 += G) {
    const float* boG = s + (size_t)g0 * 64 * HW_;
    const float* dgG = g + (size_t)g0 * 64 * HW_;

    // ---- batched front-end: 3 launches cover G batches ----
    conv1x1_3<<<dim3(64, G, 3), dim3(256), 0, stream>>>(boG, dgG, g_w, g_b, t_w, t_b,
                                                        p_w, p_b, b1, b2, b3);
    unfold_qk<<<dim3(1, 2048, 2 * G), dim3(256), 0, stream>>>(b1, b3, qbuf, kbuf, tab);
    unfold_v <<<dim3(4, NPV, G),      dim3(256), 0, stream>>>(b2, vbufp, tab);

    // ---- per-batch attention chain ----
    for (int lb = 0; lb < G; ++lb) {
      int b = g0 + lb;
      const float* bo = s + (size_t)b * 64 * HW_;
      float* ob = out + (size_t)b * 64 * HW_;
      fp16_t* qb = qbuf + (size_t)lb * NPIX * KQ;
      fp16_t* kb = kbuf + (size_t)lb * NPIX * KQ;
      bf16_t* vb = vbufp + (size_t)lb * NPV * 4096;

      // score = 10 * q k^T  (fp16, K=832, T=13), grid 256 = 1 wg/CU
      gemm256<fp16_t, float><<<dim3(256), dim3(512), 0, stream>>>(
          qb, KQ, kb, KQ, score, 4096, 16, 256, (size_t)0, KQ, 0, 10.0f);
      softmax_rows<<<dim3(4096), dim3(256), 0, stream>>>(score, att);
      // part[sp] = att[:, sp*1024:(sp+1)*1024] @ v^T  (split-K=4, K=1024, T=16, bf16 partials)
      gemm256<bf16_t, bf16_t><<<dim3(256), dim3(512), 0, stream>>>(
          att, 4096, vb, 4096, part, 1024, 4, 64, (size_t)4096 * 1024, 1024, 1024, 1.0f);
      reduce4<<<dim3(2048), dim3(256), 0, stream>>>(part, amv);
      fold_norm<<<dim3(4096), dim3(256), 0, stream>>>(amv, zi);
      out_conv<<<dim3(256), dim3(256), 0, stream>>>(zi, bo, w_w, w_b, ob);
    }
  }
}

// Round 17
// 1512.184 us; speedup vs baseline: 1.0012x; 1.0012x over previous
//
#include <hip/hip_runtime.h>
#include <cstdint>
#include <cstddef>

// ---------------- types ----------------
typedef __bf16 bf16_t;
typedef _Float16 fp16_t;
typedef bf16_t bf16x8 __attribute__((ext_vector_type(8)));
typedef fp16_t fp16x8 __attribute__((ext_vector_type(8)));
typedef bf16_t bf16x2 __attribute__((ext_vector_type(2)));
typedef fp16_t fp16x2 __attribute__((ext_vector_type(2)));
typedef float  f32x4  __attribute__((ext_vector_type(4)));
typedef float  f32x2  __attribute__((ext_vector_type(2)));

#define GAS __attribute__((address_space(1)))
#define LAS __attribute__((address_space(3)))

__device__ __forceinline__ void g2l16(const void* g, void* l) {
  // async global->LDS, 16B per lane; LDS dest is wave-uniform base + lane*16
  __builtin_amdgcn_global_load_lds((const GAS unsigned int*)g,
                                   (LAS unsigned int*)l, 16, 0, 0);
}

__device__ __forceinline__ f32x4 mfma16(bf16x8 a, bf16x8 b, f32x4 c) {
  return __builtin_amdgcn_mfma_f32_16x16x32_bf16(a, b, c, 0, 0, 0);
}
__device__ __forceinline__ f32x4 mfma16(fp16x8 a, fp16x8 b, f32x4 c) {
  return __builtin_amdgcn_mfma_f32_16x16x32_f16(a, b, c, 0, 0, 0);
}
template <typename T> struct vec8;
template <> struct vec8<bf16_t> { using t = bf16x8; };
template <> struct vec8<fp16_t> { using t = fp16x8; };

// Problem constants
#define HW_  65536      // 256*256
#define NPIX 4096       // 64*64 patch grid
#define KQ   832        // 784 real + pad to 832 (fp16 single-pass), 832 % 64 == 0
#define NPV  1024       // v rows padded to 1024 (784 real)

// ------- decode table: tab[kk] = (c*HW+(ki-1)*256+(kj-1)+257) | ki<<20 | kj<<24 | 1<<28 ----
// kk in [784,1024): 0 (invalid -> value 0). Removes /49,/7 chains from the unfold hot path.
__global__ void build_tab(int* __restrict__ tab) {
  int kk = blockIdx.x * 256 + threadIdx.x;
  int v = 0;
  if (kk < 784) {
    int c = kk / 49, r = kk - c * 49, ki = r / 7, kj = r - ki * 7;
    int off = c * HW_ + (ki - 1) * 256 + (kj - 1) + 257;   // biased, >=0, <2^20
    v = off | (ki << 20) | (kj << 24) | (1 << 28);
  }
  tab[kk] = v;
}

// ------- 1x1 convs, float2-vectorized, 3 block types (z=0: b1<-bo; 1: b2<-dg; 2: b3<-dg) ---
// Round-15 known-good body (44 VGPR, no spill), c-unroll widened 4 -> 8: 8 float2 loads
// (4KB/wave) in flight, acc = 16 x f32x2 = 32 VGPR. Total reg need ~60 — inside the
// compiler's observed ~48-64 comfort zone (round-16 lesson: >=64 acc regs get mangled).
__global__ __launch_bounds__(256) void conv1x1_3(
    const float* __restrict__ bo, const float* __restrict__ dg,
    const float* __restrict__ gw, const float* __restrict__ gb,
    const float* __restrict__ tw, const float* __restrict__ tb,
    const float* __restrict__ pw, const float* __restrict__ pb,
    fp16_t* __restrict__ b1, bf16_t* __restrict__ b2, fp16_t* __restrict__ b3)
{
  __shared__ float wS[1024], bia[16];
  int tid = threadIdx.x;
  int lb  = blockIdx.y;
  int z   = blockIdx.z;
  const float* w   = (z == 0) ? gw : (z == 1) ? tw : pw;
  const float* bb  = (z == 0) ? gb : (z == 1) ? tb : pb;
  const float* src = ((z == 0) ? bo : dg) + (size_t)lb * 64 * HW_;
  for (int i = tid; i < 1024; i += 256) wS[i] = w[i];
  if (tid < 16) bia[tid] = bb[tid];
  __syncthreads();

  size_t hw = ((size_t)blockIdx.x * 256 + tid) * 2;
  f32x2 acc[16];
#pragma unroll
  for (int o = 0; o < 16; ++o) {
    float bv = bia[o];
    acc[o] = f32x2{bv, bv};
  }
  for (int c = 0; c < 64; c += 8) {
    float2 v[8];
#pragma unroll
    for (int u = 0; u < 8; ++u)
      v[u] = *(const float2*)(src + (size_t)(c + u) * HW_ + hw);
#pragma unroll
    for (int u = 0; u < 8; ++u)
#pragma unroll
      for (int o = 0; o < 16; ++o) {
        float wv = wS[o * 64 + c + u];
        acc[o][0] = fmaf(wv, v[u].x, acc[o][0]);
        acc[o][1] = fmaf(wv, v[u].y, acc[o][1]);
      }
  }
  if (z == 1) {
    bf16_t* dst = b2 + (size_t)lb * 16 * HW_;
#pragma unroll
    for (int o = 0; o < 16; ++o) {
      bf16x2 pk;
      pk[0] = (bf16_t)acc[o][0];
      pk[1] = (bf16_t)acc[o][1];
      *(bf16x2*)(dst + (size_t)o * HW_ + hw) = pk;
    }
  } else {
    fp16_t* dst = ((z == 0) ? b1 : b3) + (size_t)lb * 16 * HW_;
#pragma unroll
    for (int o = 0; o < 16; ++o) {
      fp16x2 pk;
      pk[0] = (fp16_t)acc[o][0];
      pk[1] = (fp16_t)acc[o][1];
      *(fp16x2*)(dst + (size_t)o * HW_ + hw) = pk;
    }
  }
}

// ------- unfold q & k, table-driven, 8 gathers in flight ----------------------------------
// thread: kk in {tid+256u}, patches {i0, i0+2048}; grid (1, 2048, 2G), z = lb*2 + sel.
__global__ __launch_bounds__(256) void unfold_qk(const fp16_t* __restrict__ b1,
                                                 const fp16_t* __restrict__ b3,
                                                 fp16_t* __restrict__ qb,
                                                 fp16_t* __restrict__ kb,
                                                 const int* __restrict__ tab)
{
  int tid = threadIdx.x;
  int lb = blockIdx.z >> 1, sel = blockIdx.z & 1;
  const fp16_t* src = (sel ? b3 : b1) + (size_t)lb * 16 * HW_;
  fp16_t* dst       = (sel ? kb : qb) + (size_t)lb * NPIX * KQ;
  int i0 = blockIdx.y, i1 = i0 + 2048;
  int oy0 = i0 >> 6, ox0 = i0 & 63;
  int oy1 = i1 >> 6, ox1 = i1 & 63;
  int pb0 = oy0 * 1024 + ox0 * 4;
  int pb1 = oy1 * 1024 + ox1 * 4;
  int t[4];
#pragma unroll
  for (int u = 0; u < 4; ++u) t[u] = tab[tid + u * 256];
  fp16_t v0[4], v1[4];
#pragma unroll
  for (int u = 0; u < 4; ++u) {
    int off = (t[u] & 0xFFFFF) - 257;
    int ki  = (t[u] >> 20) & 15;
    int kj  = (t[u] >> 24) & 15;
    int vld = t[u] >> 28;
    int y0 = oy0 * 4 + ki - 1, x0 = ox0 * 4 + kj - 1;
    int y1 = oy1 * 4 + ki - 1, x1 = ox1 * 4 + kj - 1;
    v0[u] = (vld && (unsigned)y0 < 256u && (unsigned)x0 < 256u)
            ? src[pb0 + off] : (fp16_t)0.f;
    v1[u] = (vld && (unsigned)y1 < 256u && (unsigned)x1 < 256u)
            ? src[pb1 + off] : (fp16_t)0.f;
  }
#pragma unroll
  for (int u = 0; u < 4; ++u) {
    int kk = tid + u * 256;
    if (kk < KQ) {
      dst[(size_t)i0 * KQ + kk] = v0[u];
      dst[(size_t)i1 * KQ + kk] = v1[u];
    }
  }
}

// ------- v unfold, table-driven (wave-uniform row decode), 4 gathers in flight -------------
// grid (4, NPV, G): p = blockIdx.y, j = blockIdx.x*1024 + tid + 256u.
__global__ __launch_bounds__(256) void unfold_v(const bf16_t* __restrict__ src,
                                                bf16_t* __restrict__ vb,
                                                const int* __restrict__ tab)
{
  int tid = threadIdx.x;
  int p  = blockIdx.y;
  int lb = blockIdx.z;
  src += (size_t)lb * 16 * HW_;
  vb  += (size_t)lb * NPV * 4096;
  int t = tab[p];                       // wave-uniform -> scalar load
  int off = (t & 0xFFFFF) - 257;
  int ki  = (t >> 20) & 15;
  int kj  = (t >> 24) & 15;
  int vld = t >> 28;
  int jb = blockIdx.x * 1024 + tid;
  bf16_t v[4];
#pragma unroll
  for (int u = 0; u < 4; ++u) {
    int j = jb + u * 256;
    int oy = j >> 6, ox = j & 63;
    int y = oy * 4 + ki - 1, x = ox * 4 + kj - 1;
    v[u] = (vld && (unsigned)y < 256u && (unsigned)x < 256u)
           ? src[oy * 1024 + ox * 4 + off] : (bf16_t)0.f;
  }
#pragma unroll
  for (int u = 0; u < 4; ++u)
    vb[(size_t)p * 4096 + jb + u * 256] = v[u];
}

// ---------------- 256x256-tile GEMM, 8-phase schedule: C = alpha*A(MxK)*B(NxK)^T -----------
// (round-6 known-good) 8 waves (2M x 4N), BK=64 in two K-halves of 32. LDS = ring of 8 x
// 16KiB half-slots. Tile t occupies slots (t&1)*4 + {0:Ak0, 1:Bk0, 2:Ak1, 3:Bk1}.
// Per phase: {ds_read frags -> stage 1 half -> barrier -> lgkmcnt(0) -> 16 MFMA -> barrier};
// boundary vmcnt(6) per tile (vmcnt(0) at t==T-2). REQUIRES: K % 64 == 0, T = K/64 >= 3.
// OT = output element type (float or bf16_t) — bf16 halves epilogue/partial traffic.
template <typename T, typename OT>
__global__ __launch_bounds__(512, 2) void gemm256(
    const T* __restrict__ A, int lda,
    const T* __restrict__ B, int ldb,
    OT* __restrict__ C, int ldc,
    int nbn, int bps, size_t csplit, int K, int kofs, float alpha)
{
  using v8t = typename vec8<T>::t;
  __shared__ __align__(16) T lds[8][8192];   // 8 half-slots x 16 KiB = 128 KiB

  int nwg = gridDim.x, wg = blockIdx.x;
  int swz = ((nwg & 7) == 0) ? ((wg & 7) * (nwg >> 3) + (wg >> 3)) : wg;
  int s   = swz / bps;
  int rem = swz - s * bps;
  int bm  = rem / nbn, bn = rem - bm * nbn;
  A += (size_t)s * kofs;
  B += (size_t)s * kofs;
  C += (size_t)s * csplit;

  int tid  = threadIdx.x;
  int lane = tid & 63;
  int wid  = tid >> 6;
  int wr   = wid >> 2, wc = wid & 3;        // wave -> 128-row x 64-col output block
  int l16  = lane & 15;

  // staging: instr u stages cell u*512+tid; cell = kb*256+row, kb = u*2+(tid>>8),
  // row = tid&255; global k-elem offset = half_kofs + kb*8.
  const T* gA = A + (size_t)(bm * 256 + (tid & 255)) * lda + (tid >> 8) * 8;
  const T* gB = B + (size_t)(bn * 256 + (tid & 255)) * ldb + (tid >> 8) * 8;

#define STAGE(gsrc, koffe, slot) {                                   \
    const T* _s = (gsrc) + (koffe);                                  \
    g2l16(_s,      &lds[slot][(size_t)tid * 8]);                     \
    g2l16(_s + 16, &lds[slot][(size_t)(512 + tid) * 8]); }

  // fragment read offsets (elements) within a half-slot: cell = (lane>>4)*256 + row
  int aoff = ((lane >> 4) * 256 + wr * 128 + l16) * 8;
  int boff = ((lane >> 4) * 256 + wc * 64 + l16) * 8;

  f32x4 acc[8][4];
#pragma unroll
  for (int f = 0; f < 8; ++f)
#pragma unroll
    for (int q = 0; q < 4; ++q) acc[f][q] = f32x4{0.f, 0.f, 0.f, 0.f};

  int T_ = K >> 6;   // BK = 64

  // prologue: 7 halves in steady-state order
  STAGE(gB, 0, 1)        // Bk0(0)
  STAGE(gA, 0, 0)        // Ak0(0)
  STAGE(gB, 32, 3)       // Bk1(0)
  STAGE(gA, 32, 2)       // Ak1(0)
  STAGE(gB, 64, 5)       // Bk0(1)
  STAGE(gA, 64, 4)       // Ak0(1)
  STAGE(gB, 96, 7)       // Bk1(1)
  asm volatile("s_waitcnt vmcnt(6)" ::: "memory");   // tile 0 fully resident
  __builtin_amdgcn_s_barrier();

  for (int t = 0; t < T_; ++t) {
    int pi = (t & 1) * 4;          // current tile's slot base
    int po = ((t + 1) & 1) * 4;    // other parity
    const T* sAk0 = &lds[pi + 0][0];
    const T* sBk0 = &lds[pi + 1][0];
    const T* sAk1 = &lds[pi + 2][0];
    const T* sBk1 = &lds[pi + 3][0];
    v8t bg[4], af[4];

    // ---- phase 0: read B(ks0) + A(ks0, rf0-3) | stage Ak1(t+1) | MFMA q0 ----
#pragma unroll
    for (int q = 0; q < 4; ++q) bg[q] = *(const v8t*)(sBk0 + boff + q * 128);
#pragma unroll
    for (int f = 0; f < 4; ++f) af[f] = *(const v8t*)(sAk0 + aoff + f * 128);
    if (t + 1 < T_) STAGE(gA, (t + 1) * 64 + 32, po + 2)
    __builtin_amdgcn_s_barrier();
    asm volatile("s_waitcnt lgkmcnt(0)" ::: "memory");
    __builtin_amdgcn_sched_barrier(0);
    __builtin_amdgcn_s_setprio(1);
#pragma unroll
    for (int f = 0; f < 4; ++f)
#pragma unroll
      for (int q = 0; q < 4; ++q)
        acc[f][q] = mfma16(af[f], bg[q], acc[f][q]);
    __builtin_amdgcn_s_setprio(0);
    __builtin_amdgcn_s_barrier();

    // ---- phase 1: read A(ks0, rf4-7) | stage Bk0(t+2) | MFMA q1 ----
#pragma unroll
    for (int f = 0; f < 4; ++f) af[f] = *(const v8t*)(sAk0 + aoff + 512 + f * 128);
    if (t + 2 < T_) STAGE(gB, (t + 2) * 64, pi + 1)
    __builtin_amdgcn_s_barrier();
    asm volatile("s_waitcnt lgkmcnt(0)" ::: "memory");
    __builtin_amdgcn_sched_barrier(0);
    __builtin_amdgcn_s_setprio(1);
#pragma unroll
    for (int f = 0; f < 4; ++f)
#pragma unroll
      for (int q = 0; q < 4; ++q)
        acc[4 + f][q] = mfma16(af[f], bg[q], acc[4 + f][q]);
    __builtin_amdgcn_s_setprio(0);
    __builtin_amdgcn_s_barrier();

    // ---- phase 2: read B(ks1) + A(ks1, rf0-3) | stage Ak0(t+2) | MFMA q2 ----
#pragma unroll
    for (int q = 0; q < 4; ++q) bg[q] = *(const v8t*)(sBk1 + boff + q * 128);
#pragma unroll
    for (int f = 0; f < 4; ++f) af[f] = *(const v8t*)(sAk1 + aoff + f * 128);
    if (t + 2 < T_) STAGE(gA, (t + 2) * 64, pi + 0)
    __builtin_amdgcn_s_barrier();
    asm volatile("s_waitcnt lgkmcnt(0)" ::: "memory");
    __builtin_amdgcn_sched_barrier(0);
    __builtin_amdgcn_s_setprio(1);
#pragma unroll
    for (int f = 0; f < 4; ++f)
#pragma unroll
      for (int q = 0; q < 4; ++q)
        acc[f][q] = mfma16(af[f], bg[q], acc[f][q]);
    __builtin_amdgcn_s_setprio(0);
    __builtin_amdgcn_s_barrier();

    // ---- phase 3: read A(ks1, rf4-7) | stage Bk1(t+2) | MFMA q3 | boundary vmcnt ----
#pragma unroll
    for (int f = 0; f < 4; ++f) af[f] = *(const v8t*)(sAk1 + aoff + 512 + f * 128);
    if (t + 2 < T_) STAGE(gB, (t + 2) * 64 + 32, pi + 3)
    __builtin_amdgcn_s_barrier();
    asm volatile("s_waitcnt lgkmcnt(0)" ::: "memory");
    __builtin_amdgcn_sched_barrier(0);
    __builtin_amdgcn_s_setprio(1);
#pragma unroll
    for (int f = 0; f < 4; ++f)
#pragma unroll
      for (int q = 0; q < 4; ++q)
        acc[4 + f][q] = mfma16(af[f], bg[q], acc[4 + f][q]);
    __builtin_amdgcn_s_setprio(0);
    if (t < T_ - 2)       { asm volatile("s_waitcnt vmcnt(6)" ::: "memory"); }
    else if (t == T_ - 2) { asm volatile("s_waitcnt vmcnt(0)" ::: "memory"); }
    __builtin_amdgcn_s_barrier();
  }
#undef STAGE

  // C/D layout: col = lane&15, row = (lane>>4)*4 + reg ; frag rows = wr*128 + F*16
  int r0 = bm * 256 + wr * 128 + (lane >> 4) * 4;
  int c0 = bn * 256 + wc * 64 + l16;
#pragma unroll
  for (int f = 0; f < 8; ++f)
#pragma unroll
    for (int q = 0; q < 4; ++q) {
      OT* cp = C + (size_t)(r0 + f * 16) * ldc + c0 + q * 16;
#pragma unroll
      for (int r = 0; r < 4; ++r) cp[(size_t)r * ldc] = (OT)(alpha * acc[f][q][r]);
    }
}

// ---------------- fused row softmax: att = softmax(score) as bf16 ----------------
__global__ __launch_bounds__(256) void softmax_rows(const float* __restrict__ S,
                                                    bf16_t* __restrict__ Att)
{
  int row = blockIdx.x;
  int tid = threadIdx.x;
  int lane = tid & 63, wid = tid >> 6;
  const float4* Sp = (const float4*)(S + (size_t)row * 4096);
  float4 vv[4];
  float m = -3.4e38f;
#pragma unroll
  for (int u = 0; u < 4; ++u) {
    vv[u] = Sp[u * 256 + tid];
    m = fmaxf(m, fmaxf(fmaxf(vv[u].x, vv[u].y), fmaxf(vv[u].z, vv[u].w)));
  }
#pragma unroll
  for (int off = 32; off; off >>= 1) m = fmaxf(m, __shfl_xor(m, off));
  __shared__ float redm[4], reds[4];
  if (lane == 0) redm[wid] = m;
  __syncthreads();
  m = fmaxf(fmaxf(redm[0], redm[1]), fmaxf(redm[2], redm[3]));
  float ssum = 0.f;
#pragma unroll
  for (int u = 0; u < 4; ++u) {
    vv[u].x = __expf(vv[u].x - m); vv[u].y = __expf(vv[u].y - m);
    vv[u].z = __expf(vv[u].z - m); vv[u].w = __expf(vv[u].w - m);
    ssum += vv[u].x + vv[u].y + vv[u].z + vv[u].w;
  }
#pragma unroll
  for (int off = 32; off; off >>= 1) ssum += __shfl_xor(ssum, off);
  if (lane == 0) reds[wid] = ssum;
  __syncthreads();
  float inv = 1.0f / (reds[0] + reds[1] + reds[2] + reds[3]);
  ushort4* Ap = (ushort4*)(Att + (size_t)row * 4096);
#pragma unroll
  for (int u = 0; u < 4; ++u) {
    union { bf16_t b[4]; ushort4 q; } pk;
    pk.b[0] = (bf16_t)(vv[u].x * inv);
    pk.b[1] = (bf16_t)(vv[u].y * inv);
    pk.b[2] = (bf16_t)(vv[u].z * inv);
    pk.b[3] = (bf16_t)(vv[u].w * inv);
    Ap[u * 256 + tid] = pk.q;
  }
}

// ---------------- split-K reduce: amv = sum_s part[s] (bf16 partials, coalesced) -----------
__global__ __launch_bounds__(256) void reduce4(const bf16_t* __restrict__ part,
                                               float* __restrict__ amv)
{
  size_t i = ((size_t)blockIdx.x * 256 + threadIdx.x) * 8;   // over 4096*1024 elems
  const size_t S = (size_t)4096 * 1024;
  bf16x8 a = *(const bf16x8*)(part + i);
  bf16x8 b = *(const bf16x8*)(part + i + S);
  bf16x8 c = *(const bf16x8*)(part + i + 2 * S);
  bf16x8 d = *(const bf16x8*)(part + i + 3 * S);
  float o[8];
#pragma unroll
  for (int j = 0; j < 8; ++j)
    o[j] = (float)a[j] + (float)b[j] + (float)c[j] + (float)d[j];
  float4* op = (float4*)(amv + i);
  op[0] = float4{o[0], o[1], o[2], o[3]};
  op[1] = float4{o[4], o[5], o[6], o[7]};
}

// ---------------- fold (k=7,s=4,pad=3) + mask normalize -> zi[16][256][256] ----------------
__global__ __launch_bounds__(256) void fold_norm(const float* __restrict__ amv,
                                                 float* __restrict__ zi)
{
  int idx = blockIdx.x * 256 + threadIdx.x;   // c*65536 + h*256 + w
  int c = idx >> 16;
  int h = (idx >> 8) & 255;
  int w = idx & 255;
  int t = h + 3, u = w + 3;
  int oy0 = (t - 3) >> 2, oy1 = min(63, t >> 2);
  int ox0 = (u - 3) >> 2, ox1 = min(63, u >> 2);
  float sum = 0.f;
  for (int oy = oy0; oy <= oy1; ++oy) {
    int ki = t - oy * 4;
    for (int ox = ox0; ox <= ox1; ++ox) {
      int kj = u - ox * 4;
      sum += amv[(size_t)(oy * 64 + ox) * NPV + c * 49 + ki * 7 + kj];
    }
  }
  int cnt = (oy1 - oy0 + 1) * (ox1 - ox0 + 1);
  zi[idx] = sum / (float)cnt;
}

// ---------------- final: out = bo + w_w*zi + w_b ----------------
__global__ __launch_bounds__(256) void out_conv(const float* __restrict__ zi,
                                                const float* __restrict__ bo,
                                                const float* __restrict__ ww,
                                                const float* __restrict__ wb,
                                                float* __restrict__ outb)
{
  __shared__ float wws[1024], wbs[64];
  int tid = threadIdx.x;
  for (int i = tid; i < 1024; i += 256) wws[i] = ww[i];
  if (tid < 64) wbs[tid] = wb[tid];
  __syncthreads();
  int hw = blockIdx.x * 256 + tid;
  float z[16];
#pragma unroll
  for (int c = 0; c < 16; ++c) z[c] = zi[(size_t)c * HW_ + hw];
  for (int o = 0; o < 64; ++o) {
    float a = wbs[o];
#pragma unroll
    for (int c = 0; c < 16; ++c) a = fmaf(wws[o * 16 + c], z[c], a);
    outb[(size_t)o * HW_ + hw] = bo[(size_t)o * HW_ + hw] + a;
  }
}

// ---------------- host orchestration ----------------
static inline size_t alup(size_t x) { return (x + 255) & ~(size_t)255; }

extern "C" void kernel_launch(void* const* d_in, const int* in_sizes, int n_in,
                              void* d_out, int out_size, void* d_ws, size_t ws_size,
                              hipStream_t stream) {
  const float* s   = (const float*)d_in[0];
  const float* g   = (const float*)d_in[1];
  const float* g_w = (const float*)d_in[2];
  const float* g_b = (const float*)d_in[3];
  const float* t_w = (const float*)d_in[4];
  const float* t_b = (const float*)d_in[5];
  const float* p_w = (const float*)d_in[6];
  const float* p_b = (const float*)d_in[7];
  const float* w_w = (const float*)d_in[8];
  const float* w_b = (const float*)d_in[9];
  float* out = (float*)d_out;

  // Per-G front-buffer sizes + fixed middle/back sizes
  const size_t szB1 = (size_t)16 * HW_ * 2;          // fp16/bf16 conv outs (per batch)
  const size_t szQK = (size_t)NPIX * KQ * 2;         // per batch
  const size_t szV  = (size_t)NPV * 4096 * 2;        // per batch
  const size_t szSc = (size_t)NPIX * NPIX * 4;       // score (f32), part (bf16) aliases
  const size_t szAtt = (size_t)NPIX * NPIX * 2;
  const size_t szZi  = (size_t)16 * HW_ * 4;
  const size_t szAmv = (size_t)NPIX * NPV * 4;
  const size_t szTab = (size_t)1024 * 4;

  // choose largest G in {8,4,2,1} whose layout fits ws_size (deterministic)
  int G = 1;
  for (int cand = 8; cand >= 1; cand >>= 1) {
    size_t need = alup(szB1) * 3 * cand + alup(szQK) * 2 * cand + alup(szV) * cand
                + alup(szSc) + alup(szAtt) + alup(szZi) + alup(szAmv) + alup(szTab);
    if (need <= ws_size) { G = cand; break; }
  }

  uint8_t* wp = (uint8_t*)d_ws;
  fp16_t* b1    = (fp16_t*)wp; wp += alup(szB1) * G;
  bf16_t* b2    = (bf16_t*)wp; wp += alup(szB1) * G;
  fp16_t* b3    = (fp16_t*)wp; wp += alup(szB1) * G;
  fp16_t* qbuf  = (fp16_t*)wp; wp += alup(szQK) * G;
  fp16_t* kbuf  = (fp16_t*)wp; wp += alup(szQK) * G;
  bf16_t* vbufp = (bf16_t*)wp; wp += alup(szV) * G;
  float*  score = (float*)wp;  wp += alup(szSc);
  bf16_t* att   = (bf16_t*)wp; wp += alup(szAtt);
  float*  zi    = (float*)wp;  wp += alup(szZi);
  float*  amv   = (float*)wp;  wp += alup(szAmv);
  int*    tab   = (int*)wp;    wp += alup(szTab);
  bf16_t* part  = (bf16_t*)score;   // score dead after softmax; 4*4096*1024 bf16 = 32MB

  build_tab<<<dim3(4), dim3(256), 0, stream>>>(tab);

  for (int g0 = 0; g0 < 8; g0 += G) {
    const float* boG = s + (size_t)g0 * 64 * HW_;
    const float* dgG = g + (size_t)g0 * 64 * HW_;

    // ---- batched front-end: 3 launches cover G batches ----
    conv1x1_3<<<dim3(128, G, 3), dim3(256), 0, stream>>>(boG, dgG, g_w, g_b, t_w, t_b,
                                                         p_w, p_b, b1, b2, b3);
    unfold_qk<<<dim3(1, 2048, 2 * G), dim3(256), 0, stream>>>(b1, b3, qbuf, kbuf, tab);
    unfold_v <<<dim3(4, NPV, G),      dim3(256), 0, stream>>>(b2, vbufp, tab);

    // ---- per-batch attention chain ----
    for (int lb = 0; lb < G; ++lb) {
      int b = g0 + lb;
      const float* bo = s + (size_t)b * 64 * HW_;
      float* ob = out + (size_t)b * 64 * HW_;
      fp16_t* qb = qbuf + (size_t)lb * NPIX * KQ;
      fp16_t* kb = kbuf + (size_t)lb * NPIX * KQ;
      bf16_t* vb = vbufp + (size_t)lb * NPV * 4096;

      // score = 10 * q k^T  (fp16, K=832, T=13), grid 256 = 1 wg/CU
      gemm256<fp16_t, float><<<dim3(256), dim3(512), 0, stream>>>(
          qb, KQ, kb, KQ, score, 4096, 16, 256, (size_t)0, KQ, 0, 10.0f);
      softmax_rows<<<dim3(4096), dim3(256), 0, stream>>>(score, att);
      // part[sp] = att[:, sp*1024:(sp+1)*1024] @ v^T  (split-K=4, K=1024, T=16, bf16 partials)
      gemm256<bf16_t, bf16_t><<<dim3(256), dim3(512), 0, stream>>>(
          att, 4096, vb, 4096, part, 1024, 4, 64, (size_t)4096 * 1024, 1024, 1024, 1.0f);
      reduce4<<<dim3(2048), dim3(256), 0, stream>>>(part, amv);
      fold_norm<<<dim3(4096), dim3(256), 0, stream>>>(amv, zi);
      out_conv<<<dim3(256), dim3(256), 0, stream>>>(zi, bo, w_w, w_b, ob);
    }
  }
}

// Round 19
// 1387.548 us; speedup vs baseline: 1.0912x; 1.0898x over previous
//
#include <hip/hip_runtime.h>
#include <cstdint>
#include <cstddef>

// ---------------- types ----------------
typedef __bf16 bf16_t;
typedef _Float16 fp16_t;
typedef bf16_t bf16x8 __attribute__((ext_vector_type(8)));
typedef fp16_t fp16x8 __attribute__((ext_vector_type(8)));
typedef bf16_t bf16x2 __attribute__((ext_vector_type(2)));
typedef fp16_t fp16x2 __attribute__((ext_vector_type(2)));
typedef float  f32x4  __attribute__((ext_vector_type(4)));
typedef float  f32x2  __attribute__((ext_vector_type(2)));

#define GAS __attribute__((address_space(1)))
#define LAS __attribute__((address_space(3)))

__device__ __forceinline__ void g2l16(const void* g, void* l) {
  // async global->LDS, 16B per lane; LDS dest is wave-uniform base + lane*16
  __builtin_amdgcn_global_load_lds((const GAS unsigned int*)g,
                                   (LAS unsigned int*)l, 16, 0, 0);
}

__device__ __forceinline__ f32x4 mfma16(bf16x8 a, bf16x8 b, f32x4 c) {
  return __builtin_amdgcn_mfma_f32_16x16x32_bf16(a, b, c, 0, 0, 0);
}
__device__ __forceinline__ f32x4 mfma16(fp16x8 a, fp16x8 b, f32x4 c) {
  return __builtin_amdgcn_mfma_f32_16x16x32_f16(a, b, c, 0, 0, 0);
}
template <typename T> struct vec8;
template <> struct vec8<bf16_t> { using t = bf16x8; };
template <> struct vec8<fp16_t> { using t = fp16x8; };

// Problem constants
#define HW_  65536      // 256*256
#define NPIX 4096       // 64*64 patch grid
#define KQ   832        // 784 real + pad to 832 (fp16 single-pass), 832 % 64 == 0
#define NPV  1024       // v rows padded to 1024 (784 real)

// ------- decode table: tab[kk] = (c*HW+(ki-1)*256+(kj-1)+257) | ki<<20 | kj<<24 | 1<<28 ----
__global__ void build_tab(int* __restrict__ tab) {
  int kk = blockIdx.x * 256 + threadIdx.x;
  int v = 0;
  if (kk < 784) {
    int c = kk / 49, r = kk - c * 49, ki = r / 7, kj = r - ki * 7;
    int off = c * HW_ + (ki - 1) * 256 + (kj - 1) + 257;   // biased, >=0, <2^20
    v = off | (ki << 20) | (kj << 24) | (1 << 28);
  }
  tab[kk] = v;
}

// ------- 1x1 convs, float2-vectorized, 3 block types (z=0: b1<-bo; 1: b2<-dg; 2: b3<-dg) ---
// Round-17 best: 8 float2 loads (4KB/wave) in flight, acc = 16 x f32x2 (72 VGPR, no spill).
__global__ __launch_bounds__(256) void conv1x1_3(
    const float* __restrict__ bo, const float* __restrict__ dg,
    const float* __restrict__ gw, const float* __restrict__ gb,
    const float* __restrict__ tw, const float* __restrict__ tb,
    const float* __restrict__ pw, const float* __restrict__ pb,
    fp16_t* __restrict__ b1, bf16_t* __restrict__ b2, fp16_t* __restrict__ b3)
{
  __shared__ float wS[1024], bia[16];
  int tid = threadIdx.x;
  int lb  = blockIdx.y;
  int z   = blockIdx.z;
  const float* w   = (z == 0) ? gw : (z == 1) ? tw : pw;
  const float* bb  = (z == 0) ? gb : (z == 1) ? tb : pb;
  const float* src = ((z == 0) ? bo : dg) + (size_t)lb * 64 * HW_;
  for (int i = tid; i < 1024; i += 256) wS[i] = w[i];
  if (tid < 16) bia[tid] = bb[tid];
  __syncthreads();

  size_t hw = ((size_t)blockIdx.x * 256 + tid) * 2;
  f32x2 acc[16];
#pragma unroll
  for (int o = 0; o < 16; ++o) {
    float bv = bia[o];
    acc[o] = f32x2{bv, bv};
  }
  for (int c = 0; c < 64; c += 8) {
    float2 v[8];
#pragma unroll
    for (int u = 0; u < 8; ++u)
      v[u] = *(const float2*)(src + (size_t)(c + u) * HW_ + hw);
#pragma unroll
    for (int u = 0; u < 8; ++u)
#pragma unroll
      for (int o = 0; o < 16; ++o) {
        float wv = wS[o * 64 + c + u];
        acc[o][0] = fmaf(wv, v[u].x, acc[o][0]);
        acc[o][1] = fmaf(wv, v[u].y, acc[o][1]);
      }
  }
  if (z == 1) {
    bf16_t* dst = b2 + (size_t)lb * 16 * HW_;
#pragma unroll
    for (int o = 0; o < 16; ++o) {
      bf16x2 pk;
      pk[0] = (bf16_t)acc[o][0];
      pk[1] = (bf16_t)acc[o][1];
      *(bf16x2*)(dst + (size_t)o * HW_ + hw) = pk;
    }
  } else {
    fp16_t* dst = ((z == 0) ? b1 : b3) + (size_t)lb * 16 * HW_;
#pragma unroll
    for (int o = 0; o < 16; ++o) {
      fp16x2 pk;
      pk[0] = (fp16_t)acc[o][0];
      pk[1] = (fp16_t)acc[o][1];
      *(fp16x2*)(dst + (size_t)o * HW_ + hw) = pk;
    }
  }
}

// ------- unfold q & k, table-driven, 8 gathers in flight ----------------------------------
__global__ __launch_bounds__(256) void unfold_qk(const fp16_t* __restrict__ b1,
                                                 const fp16_t* __restrict__ b3,
                                                 fp16_t* __restrict__ qb,
                                                 fp16_t* __restrict__ kb,
                                                 const int* __restrict__ tab)
{
  int tid = threadIdx.x;
  int lb = blockIdx.z >> 1, sel = blockIdx.z & 1;
  const fp16_t* src = (sel ? b3 : b1) + (size_t)lb * 16 * HW_;
  fp16_t* dst       = (sel ? kb : qb) + (size_t)lb * NPIX * KQ;
  int i0 = blockIdx.y, i1 = i0 + 2048;
  int oy0 = i0 >> 6, ox0 = i0 & 63;
  int oy1 = i1 >> 6, ox1 = i1 & 63;
  int pb0 = oy0 * 1024 + ox0 * 4;
  int pb1 = oy1 * 1024 + ox1 * 4;
  int t[4];
#pragma unroll
  for (int u = 0; u < 4; ++u) t[u] = tab[tid + u * 256];
  fp16_t v0[4], v1[4];
#pragma unroll
  for (int u = 0; u < 4; ++u) {
    int off = (t[u] & 0xFFFFF) - 257;
    int ki  = (t[u] >> 20) & 15;
    int kj  = (t[u] >> 24) & 15;
    int vld = t[u] >> 28;
    int y0 = oy0 * 4 + ki - 1, x0 = ox0 * 4 + kj - 1;
    int y1 = oy1 * 4 + ki - 1, x1 = ox1 * 4 + kj - 1;
    v0[u] = (vld && (unsigned)y0 < 256u && (unsigned)x0 < 256u)
            ? src[pb0 + off] : (fp16_t)0.f;
    v1[u] = (vld && (unsigned)y1 < 256u && (unsigned)x1 < 256u)
            ? src[pb1 + off] : (fp16_t)0.f;
  }
#pragma unroll
  for (int u = 0; u < 4; ++u) {
    int kk = tid + u * 256;
    if (kk < KQ) {
      dst[(size_t)i0 * KQ + kk] = v0[u];
      dst[(size_t)i1 * KQ + kk] = v1[u];
    }
  }
}

// ------- v unfold, table-driven (wave-uniform row decode), 4 gathers in flight -------------
__global__ __launch_bounds__(256) void unfold_v(const bf16_t* __restrict__ src,
                                                bf16_t* __restrict__ vb,
                                                const int* __restrict__ tab)
{
  int tid = threadIdx.x;
  int p  = blockIdx.y;
  int lb = blockIdx.z;
  src += (size_t)lb * 16 * HW_;
  vb  += (size_t)lb * NPV * 4096;
  int t = tab[p];                       // wave-uniform -> scalar load
  int off = (t & 0xFFFFF) - 257;
  int ki  = (t >> 20) & 15;
  int kj  = (t >> 24) & 15;
  int vld = t >> 28;
  int jb = blockIdx.x * 1024 + tid;
  bf16_t v[4];
#pragma unroll
  for (int u = 0; u < 4; ++u) {
    int j = jb + u * 256;
    int oy = j >> 6, ox = j & 63;
    int y = oy * 4 + ki - 1, x = ox * 4 + kj - 1;
    v[u] = (vld && (unsigned)y < 256u && (unsigned)x < 256u)
           ? src[oy * 1024 + ox * 4 + off] : (bf16_t)0.f;
  }
#pragma unroll
  for (int u = 0; u < 4; ++u)
    vb[(size_t)p * 4096 + jb + u * 256] = v[u];
}

// ---------------- 256x256-tile GEMM, 8-phase, batched: C = alpha*A*B^T ---------------------
// (round-6 known-good schedule) + generalized batch/split decode:
//   u = swz/bps -> (bat = u/nspl, spl = u%nspl); tile = swz%bps -> (bm,bn).
//   A += bat*abat + spl*kofs; B += bat*bbat + spl*kofs; C += bat*cbat + spl*csplit.
// REQUIRES: K % 64 == 0, T = K/64 >= 3; gridDim.x = nbat*nspl*bps.
template <typename T, typename OT>
__global__ __launch_bounds__(512, 2) void gemm256(
    const T* __restrict__ A, int lda,
    const T* __restrict__ B, int ldb,
    OT* __restrict__ C, int ldc,
    int nbn, int bps, size_t csplit, int K, int kofs, float alpha,
    int nspl, size_t abat, size_t bbat, size_t cbat)
{
  using v8t = typename vec8<T>::t;
  __shared__ __align__(16) T lds[8][8192];   // 8 half-slots x 16 KiB = 128 KiB

  int nwg = gridDim.x, wg = blockIdx.x;
  int swz = ((nwg & 7) == 0) ? ((wg & 7) * (nwg >> 3) + (wg >> 3)) : wg;
  int u   = swz / bps;
  int rem = swz - u * bps;
  int bat = u / nspl, spl = u - bat * nspl;
  int bm  = rem / nbn, bn = rem - bm * nbn;
  A += (size_t)bat * abat + (size_t)spl * (size_t)kofs;
  B += (size_t)bat * bbat + (size_t)spl * (size_t)kofs;
  C += (size_t)bat * cbat + (size_t)spl * csplit;

  int tid  = threadIdx.x;
  int lane = tid & 63;
  int wid  = tid >> 6;
  int wr   = wid >> 2, wc = wid & 3;        // wave -> 128-row x 64-col output block
  int l16  = lane & 15;

  const T* gA = A + (size_t)(bm * 256 + (tid & 255)) * lda + (tid >> 8) * 8;
  const T* gB = B + (size_t)(bn * 256 + (tid & 255)) * ldb + (tid >> 8) * 8;

#define STAGE(gsrc, koffe, slot) {                                   \
    const T* _s = (gsrc) + (koffe);                                  \
    g2l16(_s,      &lds[slot][(size_t)tid * 8]);                     \
    g2l16(_s + 16, &lds[slot][(size_t)(512 + tid) * 8]); }

  int aoff = ((lane >> 4) * 256 + wr * 128 + l16) * 8;
  int boff = ((lane >> 4) * 256 + wc * 64 + l16) * 8;

  f32x4 acc[8][4];
#pragma unroll
  for (int f = 0; f < 8; ++f)
#pragma unroll
    for (int q = 0; q < 4; ++q) acc[f][q] = f32x4{0.f, 0.f, 0.f, 0.f};

  int T_ = K >> 6;   // BK = 64

  // prologue: 7 halves in steady-state order
  STAGE(gB, 0, 1)        // Bk0(0)
  STAGE(gA, 0, 0)        // Ak0(0)
  STAGE(gB, 32, 3)       // Bk1(0)
  STAGE(gA, 32, 2)       // Ak1(0)
  STAGE(gB, 64, 5)       // Bk0(1)
  STAGE(gA, 64, 4)       // Ak0(1)
  STAGE(gB, 96, 7)       // Bk1(1)
  asm volatile("s_waitcnt vmcnt(6)" ::: "memory");   // tile 0 fully resident
  __builtin_amdgcn_s_barrier();

  for (int t = 0; t < T_; ++t) {
    int pi = (t & 1) * 4;          // current tile's slot base
    int po = ((t + 1) & 1) * 4;    // other parity
    const T* sAk0 = &lds[pi + 0][0];
    const T* sBk0 = &lds[pi + 1][0];
    const T* sAk1 = &lds[pi + 2][0];
    const T* sBk1 = &lds[pi + 3][0];
    v8t bg[4], af[4];

    // ---- phase 0: read B(ks0) + A(ks0, rf0-3) | stage Ak1(t+1) | MFMA q0 ----
#pragma unroll
    for (int q = 0; q < 4; ++q) bg[q] = *(const v8t*)(sBk0 + boff + q * 128);
#pragma unroll
    for (int f = 0; f < 4; ++f) af[f] = *(const v8t*)(sAk0 + aoff + f * 128);
    if (t + 1 < T_) STAGE(gA, (t + 1) * 64 + 32, po + 2)
    __builtin_amdgcn_s_barrier();
    asm volatile("s_waitcnt lgkmcnt(0)" ::: "memory");
    __builtin_amdgcn_sched_barrier(0);
    __builtin_amdgcn_s_setprio(1);
#pragma unroll
    for (int f = 0; f < 4; ++f)
#pragma unroll
      for (int q = 0; q < 4; ++q)
        acc[f][q] = mfma16(af[f], bg[q], acc[f][q]);
    __builtin_amdgcn_s_setprio(0);
    __builtin_amdgcn_s_barrier();

    // ---- phase 1: read A(ks0, rf4-7) | stage Bk0(t+2) | MFMA q1 ----
#pragma unroll
    for (int f = 0; f < 4; ++f) af[f] = *(const v8t*)(sAk0 + aoff + 512 + f * 128);
    if (t + 2 < T_) STAGE(gB, (t + 2) * 64, pi + 1)
    __builtin_amdgcn_s_barrier();
    asm volatile("s_waitcnt lgkmcnt(0)" ::: "memory");
    __builtin_amdgcn_sched_barrier(0);
    __builtin_amdgcn_s_setprio(1);
#pragma unroll
    for (int f = 0; f < 4; ++f)
#pragma unroll
      for (int q = 0; q < 4; ++q)
        acc[4 + f][q] = mfma16(af[f], bg[q], acc[4 + f][q]);
    __builtin_amdgcn_s_setprio(0);
    __builtin_amdgcn_s_barrier();

    // ---- phase 2: read B(ks1) + A(ks1, rf0-3) | stage Ak0(t+2) | MFMA q2 ----
#pragma unroll
    for (int q = 0; q < 4; ++q) bg[q] = *(const v8t*)(sBk1 + boff + q * 128);
#pragma unroll
    for (int f = 0; f < 4; ++f) af[f] = *(const v8t*)(sAk1 + aoff + f * 128);
    if (t + 2 < T_) STAGE(gA, (t + 2) * 64, pi + 0)
    __builtin_amdgcn_s_barrier();
    asm volatile("s_waitcnt lgkmcnt(0)" ::: "memory");
    __builtin_amdgcn_sched_barrier(0);
    __builtin_amdgcn_s_setprio(1);
#pragma unroll
    for (int f = 0; f < 4; ++f)
#pragma unroll
      for (int q = 0; q < 4; ++q)
        acc[f][q] = mfma16(af[f], bg[q], acc[f][q]);
    __builtin_amdgcn_s_setprio(0);
    __builtin_amdgcn_s_barrier();

    // ---- phase 3: read A(ks1, rf4-7) | stage Bk1(t+2) | MFMA q3 | boundary vmcnt ----
#pragma unroll
    for (int f = 0; f < 4; ++f) af[f] = *(const v8t*)(sAk1 + aoff + 512 + f * 128);
    if (t + 2 < T_) STAGE(gB, (t + 2) * 64 + 32, pi + 3)
    __builtin_amdgcn_s_barrier();
    asm volatile("s_waitcnt lgkmcnt(0)" ::: "memory");
    __builtin_amdgcn_sched_barrier(0);
    __builtin_amdgcn_s_setprio(1);
#pragma unroll
    for (int f = 0; f < 4; ++f)
#pragma unroll
      for (int q = 0; q < 4; ++q)
        acc[4 + f][q] = mfma16(af[f], bg[q], acc[4 + f][q]);
    __builtin_amdgcn_s_setprio(0);
    if (t < T_ - 2)       { asm volatile("s_waitcnt vmcnt(6)" ::: "memory"); }
    else if (t == T_ - 2) { asm volatile("s_waitcnt vmcnt(0)" ::: "memory"); }
    __builtin_amdgcn_s_barrier();
  }
#undef STAGE

  // C/D layout: col = lane&15, row = (lane>>4)*4 + reg ; frag rows = wr*128 + F*16
  int r0 = bm * 256 + wr * 128 + (lane >> 4) * 4;
  int c0 = bn * 256 + wc * 64 + l16;
#pragma unroll
  for (int f = 0; f < 8; ++f)
#pragma unroll
    for (int q = 0; q < 4; ++q) {
      OT* cp = C + (size_t)(r0 + f * 16) * ldc + c0 + q * 16;
#pragma unroll
      for (int r = 0; r < 4; ++r) cp[(size_t)r * ldc] = (OT)(alpha * acc[f][q][r]);
    }
}

// ---------------- fused row softmax (batched over blockIdx.y) ----------------
__global__ __launch_bounds__(256) void softmax_rows(const float* __restrict__ S,
                                                    bf16_t* __restrict__ Att)
{
  S   += (size_t)blockIdx.y * NPIX * 4096;
  Att += (size_t)blockIdx.y * NPIX * 4096;
  int row = blockIdx.x;
  int tid = threadIdx.x;
  int lane = tid & 63, wid = tid >> 6;
  const float4* Sp = (const float4*)(S + (size_t)row * 4096);
  float4 vv[4];
  float m = -3.4e38f;
#pragma unroll
  for (int u = 0; u < 4; ++u) {
    vv[u] = Sp[u * 256 + tid];
    m = fmaxf(m, fmaxf(fmaxf(vv[u].x, vv[u].y), fmaxf(vv[u].z, vv[u].w)));
  }
#pragma unroll
  for (int off = 32; off; off >>= 1) m = fmaxf(m, __shfl_xor(m, off));
  __shared__ float redm[4], reds[4];
  if (lane == 0) redm[wid] = m;
  __syncthreads();
  m = fmaxf(fmaxf(redm[0], redm[1]), fmaxf(redm[2], redm[3]));
  float ssum = 0.f;
#pragma unroll
  for (int u = 0; u < 4; ++u) {
    vv[u].x = __expf(vv[u].x - m); vv[u].y = __expf(vv[u].y - m);
    vv[u].z = __expf(vv[u].z - m); vv[u].w = __expf(vv[u].w - m);
    ssum += vv[u].x + vv[u].y + vv[u].z + vv[u].w;
  }
#pragma unroll
  for (int off = 32; off; off >>= 1) ssum += __shfl_xor(ssum, off);
  if (lane == 0) reds[wid] = ssum;
  __syncthreads();
  float inv = 1.0f / (reds[0] + reds[1] + reds[2] + reds[3]);
  ushort4* Ap = (ushort4*)(Att + (size_t)row * 4096);
#pragma unroll
  for (int u = 0; u < 4; ++u) {
    union { bf16_t b[4]; ushort4 q; } pk;
    pk.b[0] = (bf16_t)(vv[u].x * inv);
    pk.b[1] = (bf16_t)(vv[u].y * inv);
    pk.b[2] = (bf16_t)(vv[u].z * inv);
    pk.b[3] = (bf16_t)(vv[u].w * inv);
    Ap[u * 256 + tid] = pk.q;
  }
}

// ---------------- split-K reduce (batched over blockIdx.y; slot stride = 4*4096*1024) ------
__global__ __launch_bounds__(256) void reduce4(const bf16_t* __restrict__ part,
                                               float* __restrict__ amv)
{
  part += (size_t)blockIdx.y * 4 * 4096 * 1024;   // matches gemm2 cbat exactly
  amv  += (size_t)blockIdx.y * 4096 * 1024;
  size_t i = ((size_t)blockIdx.x * 256 + threadIdx.x) * 8;   // over 4096*1024 elems
  const size_t S = (size_t)4096 * 1024;
  bf16x8 a = *(const bf16x8*)(part + i);
  bf16x8 b = *(const bf16x8*)(part + i + S);
  bf16x8 c = *(const bf16x8*)(part + i + 2 * S);
  bf16x8 d = *(const bf16x8*)(part + i + 3 * S);
  float o[8];
#pragma unroll
  for (int j = 0; j < 8; ++j)
    o[j] = (float)a[j] + (float)b[j] + (float)c[j] + (float)d[j];
  float4* op = (float4*)(amv + i);
  op[0] = float4{o[0], o[1], o[2], o[3]};
  op[1] = float4{o[4], o[5], o[6], o[7]};
}

// ---------------- fold + mask normalize (batched over blockIdx.y) ----------------
__global__ __launch_bounds__(256) void fold_norm(const float* __restrict__ amv,
                                                 float* __restrict__ zi)
{
  amv += (size_t)blockIdx.y * 4096 * 1024;
  zi  += (size_t)blockIdx.y * 16 * HW_;
  int idx = blockIdx.x * 256 + threadIdx.x;   // c*65536 + h*256 + w
  int c = idx >> 16;
  int h = (idx >> 8) & 255;
  int w = idx & 255;
  int t = h + 3, u = w + 3;
  int oy0 = (t - 3) >> 2, oy1 = min(63, t >> 2);
  int ox0 = (u - 3) >> 2, ox1 = min(63, u >> 2);
  float sum = 0.f;
  for (int oy = oy0; oy <= oy1; ++oy) {
    int ki = t - oy * 4;
    for (int ox = ox0; ox <= ox1; ++ox) {
      int kj = u - ox * 4;
      sum += amv[(size_t)(oy * 64 + ox) * NPV + c * 49 + ki * 7 + kj];
    }
  }
  int cnt = (oy1 - oy0 + 1) * (ox1 - ox0 + 1);
  zi[idx] = sum / (float)cnt;
}

// ---------------- final conv (batched over blockIdx.y) ----------------
__global__ __launch_bounds__(256) void out_conv(const float* __restrict__ zi,
                                                const float* __restrict__ bo,
                                                const float* __restrict__ ww,
                                                const float* __restrict__ wb,
                                                float* __restrict__ outb)
{
  zi   += (size_t)blockIdx.y * 16 * HW_;
  bo   += (size_t)blockIdx.y * 64 * HW_;
  outb += (size_t)blockIdx.y * 64 * HW_;
  __shared__ float wws[1024], wbs[64];
  int tid = threadIdx.x;
  for (int i = tid; i < 1024; i += 256) wws[i] = ww[i];
  if (tid < 64) wbs[tid] = wb[tid];
  __syncthreads();
  int hw = blockIdx.x * 256 + tid;
  float z[16];
#pragma unroll
  for (int c = 0; c < 16; ++c) z[c] = zi[(size_t)c * HW_ + hw];
  for (int o = 0; o < 64; ++o) {
    float a = wbs[o];
#pragma unroll
    for (int c = 0; c < 16; ++c) a = fmaf(wws[o * 16 + c], z[c], a);
    outb[(size_t)o * HW_ + hw] = bo[(size_t)o * HW_ + hw] + a;
  }
}

// ---------------- host orchestration ----------------
static inline size_t alup(size_t x) { return (x + 255) & ~(size_t)255; }

extern "C" void kernel_launch(void* const* d_in, const int* in_sizes, int n_in,
                              void* d_out, int out_size, void* d_ws, size_t ws_size,
                              hipStream_t stream) {
  const float* s   = (const float*)d_in[0];
  const float* g   = (const float*)d_in[1];
  const float* g_w = (const float*)d_in[2];
  const float* g_b = (const float*)d_in[3];
  const float* t_w = (const float*)d_in[4];
  const float* t_b = (const float*)d_in[5];
  const float* p_w = (const float*)d_in[6];
  const float* p_b = (const float*)d_in[7];
  const float* w_w = (const float*)d_in[8];
  const float* w_b = (const float*)d_in[9];
  float* out = (float*)d_out;

  const size_t szB1 = (size_t)16 * HW_ * 2;          // fp16/bf16 conv outs (per batch)
  const size_t szQK = (size_t)NPIX * KQ * 2;         // per batch
  const size_t szV  = (size_t)NPV * 4096 * 2;        // per batch
  const size_t szSc = (size_t)NPIX * 4096 * 4;       // per chain slot (f32); part aliases
  const size_t szAtt = (size_t)NPIX * 4096 * 2;
  const size_t szZi  = (size_t)16 * HW_ * 4;
  const size_t szAmv = (size_t)NPIX * NPV * 4;
  const size_t szTab = (size_t)1024 * 4;

  // choose largest G in {8,4,2,1}; chain depth CD = 2 when G >= 2
  int G = 1;
  for (int cand = 8; cand >= 1; cand >>= 1) {
    int cd = cand >= 2 ? 2 : 1;
    size_t need = alup(szB1) * 3 * cand + alup(szQK) * 2 * cand + alup(szV) * cand
                + (size_t)cd * (alup(szSc) + alup(szAtt) + alup(szZi) + alup(szAmv))
                + alup(szTab);
    if (need <= ws_size) { G = cand; break; }
  }
  int CD = G >= 2 ? 2 : 1;

  uint8_t* wp = (uint8_t*)d_ws;
  fp16_t* b1    = (fp16_t*)wp; wp += alup(szB1) * G;
  bf16_t* b2    = (bf16_t*)wp; wp += alup(szB1) * G;
  fp16_t* b3    = (fp16_t*)wp; wp += alup(szB1) * G;
  fp16_t* qbuf  = (fp16_t*)wp; wp += alup(szQK) * G;
  fp16_t* kbuf  = (fp16_t*)wp; wp += alup(szQK) * G;
  bf16_t* vbufp = (bf16_t*)wp; wp += alup(szV) * G;
  float*  score = (float*)wp;  wp += alup(szSc) * CD;   // contiguous CD slots
  bf16_t* att   = (bf16_t*)wp; wp += alup(szAtt) * CD;
  float*  zi    = (float*)wp;  wp += alup(szZi) * CD;
  float*  amv   = (float*)wp;  wp += alup(szAmv) * CD;
  int*    tab   = (int*)wp;    wp += alup(szTab);
  bf16_t* part  = (bf16_t*)score;   // CD compact 32MiB part slots inside score region

  // slot strides in ELEMENTS (alup is identity here: all sizes are 256-multiples)
  const size_t SCS  = szSc / 4;                 // score slot stride (f32) = NPIX*4096
  const size_t ATTS = szAtt / 2;                // att slot stride (bf16) = NPIX*4096
  const size_t QKS  = (size_t)NPIX * KQ;
  const size_t VBS  = (size_t)NPV * 4096;
  const size_t PARTSLOT = (size_t)4 * 4096 * 1024;  // bf16 elems; 2 slots = 64MiB = score[0]

  build_tab<<<dim3(4), dim3(256), 0, stream>>>(tab);

  for (int g0 = 0; g0 < 8; g0 += G) {
    const float* boG = s + (size_t)g0 * 64 * HW_;
    const float* dgG = g + (size_t)g0 * 64 * HW_;

    conv1x1_3<<<dim3(128, G, 3), dim3(256), 0, stream>>>(boG, dgG, g_w, g_b, t_w, t_b,
                                                         p_w, p_b, b1, b2, b3);
    unfold_qk<<<dim3(1, 2048, 2 * G), dim3(256), 0, stream>>>(b1, b3, qbuf, kbuf, tab);
    unfold_v <<<dim3(4, NPV, G),      dim3(256), 0, stream>>>(b2, vbufp, tab);

    for (int lb = 0; lb < G; lb += CD) {
      int cd = (G - lb >= CD) ? CD : 1;
      fp16_t* qb = qbuf + (size_t)lb * QKS;
      fp16_t* kb = kbuf + (size_t)lb * QKS;
      bf16_t* vb = vbufp + (size_t)lb * VBS;
      const float* bo = s + (size_t)(g0 + lb) * 64 * HW_;
      float* ob = out + (size_t)(g0 + lb) * 64 * HW_;

      // score[bat] = 10 * q[bat] k[bat]^T   (fp16, K=832, T=13)
      gemm256<fp16_t, float><<<dim3(256 * cd), dim3(512), 0, stream>>>(
          qb, KQ, kb, KQ, score, 4096,
          16, 256, (size_t)0, KQ, 0, 10.0f,
          1, QKS, QKS, SCS);
      softmax_rows<<<dim3(4096, cd), dim3(256), 0, stream>>>(score, att);
      // part[bat][spl] = att[bat][:, spl*1024+...] @ v[bat]^T  (split-K=4, bf16 partials)
      // cbat = PARTSLOT matches reduce4's batch stride exactly (round-18 NaN fix).
      gemm256<bf16_t, bf16_t><<<dim3(256 * cd), dim3(512), 0, stream>>>(
          att, 4096, vb, 4096, part, 1024,
          4, 64, (size_t)4096 * 1024, 1024, 1024, 1.0f,
          4, ATTS, VBS, PARTSLOT);
      reduce4<<<dim3(2048, cd), dim3(256), 0, stream>>>(part, amv);
      fold_norm<<<dim3(4096, cd), dim3(256), 0, stream>>>(amv, zi);
      out_conv<<<dim3(256, cd), dim3(256), 0, stream>>>(zi, bo, w_w, w_b, ob);
    }
  }
}

// Round 20
// 1385.973 us; speedup vs baseline: 1.0924x; 1.0011x over previous
//
#include <hip/hip_runtime.h>
#include <cstdint>
#include <cstddef>

// ---------------- types ----------------
typedef __bf16 bf16_t;
typedef _Float16 fp16_t;
typedef bf16_t bf16x8 __attribute__((ext_vector_type(8)));
typedef fp16_t fp16x8 __attribute__((ext_vector_type(8)));
typedef bf16_t bf16x2 __attribute__((ext_vector_type(2)));
typedef fp16_t fp16x2 __attribute__((ext_vector_type(2)));
typedef float  f32x4  __attribute__((ext_vector_type(4)));
typedef float  f32x2  __attribute__((ext_vector_type(2)));

#define GAS __attribute__((address_space(1)))
#define LAS __attribute__((address_space(3)))

__device__ __forceinline__ void g2l16(const void* g, void* l) {
  // async global->LDS, 16B per lane; LDS dest is wave-uniform base + lane*16
  __builtin_amdgcn_global_load_lds((const GAS unsigned int*)g,
                                   (LAS unsigned int*)l, 16, 0, 0);
}

__device__ __forceinline__ f32x4 mfma16(bf16x8 a, bf16x8 b, f32x4 c) {
  return __builtin_amdgcn_mfma_f32_16x16x32_bf16(a, b, c, 0, 0, 0);
}
__device__ __forceinline__ f32x4 mfma16(fp16x8 a, fp16x8 b, f32x4 c) {
  return __builtin_amdgcn_mfma_f32_16x16x32_f16(a, b, c, 0, 0, 0);
}
template <typename T> struct vec8;
template <> struct vec8<bf16_t> { using t = bf16x8; };
template <> struct vec8<fp16_t> { using t = fp16x8; };

// Problem constants
#define HW_  65536      // 256*256
#define NPIX 4096       // 64*64 patch grid
#define KQ   832        // 784 real + pad to 832 (fp16 single-pass), 832 % 64 == 0
#define NPV  1024       // v rows padded to 1024 (784 real)

// ------- decode table: tab[kk] = (c*HW+(ki-1)*256+(kj-1)+257) | ki<<20 | kj<<24 | 1<<28 ----
__global__ void build_tab(int* __restrict__ tab) {
  int kk = blockIdx.x * 256 + threadIdx.x;
  int v = 0;
  if (kk < 784) {
    int c = kk / 49, r = kk - c * 49, ki = r / 7, kj = r - ki * 7;
    int off = c * HW_ + (ki - 1) * 256 + (kj - 1) + 257;   // biased, >=0, <2^20
    v = off | (ki << 20) | (kj << 24) | (1 << 28);
  }
  tab[kk] = v;
}

// ------- 1x1 convs, float2-vectorized; TYPE IN FASTEST GRID DIM for dg L2/L3 reuse ---------
// type = blockIdx.x % 3 (0: b1<-bo; 1: b2<-dg; 2: b3<-dg); xblk = blockIdx.x / 3.
// z=1/z=2 blocks reading the same dg lines now dispatch adjacently -> second read cache-hits.
// Round-17 body: 8 float2 loads (4KB/wave) in flight, acc = 16 x f32x2 (72 VGPR, no spill).
__global__ __launch_bounds__(256) void conv1x1_3(
    const float* __restrict__ bo, const float* __restrict__ dg,
    const float* __restrict__ gw, const float* __restrict__ gb,
    const float* __restrict__ tw, const float* __restrict__ tb,
    const float* __restrict__ pw, const float* __restrict__ pb,
    fp16_t* __restrict__ b1, bf16_t* __restrict__ b2, fp16_t* __restrict__ b3)
{
  __shared__ float wS[1024], bia[16];
  int tid  = threadIdx.x;
  int lb   = blockIdx.y;
  int z    = blockIdx.x % 3;
  int xblk = blockIdx.x / 3;
  const float* w   = (z == 0) ? gw : (z == 1) ? tw : pw;
  const float* bb  = (z == 0) ? gb : (z == 1) ? tb : pb;
  const float* src = ((z == 0) ? bo : dg) + (size_t)lb * 64 * HW_;
  for (int i = tid; i < 1024; i += 256) wS[i] = w[i];
  if (tid < 16) bia[tid] = bb[tid];
  __syncthreads();

  size_t hw = ((size_t)xblk * 256 + tid) * 2;
  f32x2 acc[16];
#pragma unroll
  for (int o = 0; o < 16; ++o) {
    float bv = bia[o];
    acc[o] = f32x2{bv, bv};
  }
  for (int c = 0; c < 64; c += 8) {
    float2 v[8];
#pragma unroll
    for (int u = 0; u < 8; ++u)
      v[u] = *(const float2*)(src + (size_t)(c + u) * HW_ + hw);
#pragma unroll
    for (int u = 0; u < 8; ++u)
#pragma unroll
      for (int o = 0; o < 16; ++o) {
        float wv = wS[o * 64 + c + u];
        acc[o][0] = fmaf(wv, v[u].x, acc[o][0]);
        acc[o][1] = fmaf(wv, v[u].y, acc[o][1]);
      }
  }
  if (z == 1) {
    bf16_t* dst = b2 + (size_t)lb * 16 * HW_;
#pragma unroll
    for (int o = 0; o < 16; ++o) {
      bf16x2 pk;
      pk[0] = (bf16_t)acc[o][0];
      pk[1] = (bf16_t)acc[o][1];
      *(bf16x2*)(dst + (size_t)o * HW_ + hw) = pk;
    }
  } else {
    fp16_t* dst = ((z == 0) ? b1 : b3) + (size_t)lb * 16 * HW_;
#pragma unroll
    for (int o = 0; o < 16; ++o) {
      fp16x2 pk;
      pk[0] = (fp16_t)acc[o][0];
      pk[1] = (fp16_t)acc[o][1];
      *(fp16x2*)(dst + (size_t)o * HW_ + hw) = pk;
    }
  }
}

// ------- unfold q & k, table-driven, 8 gathers in flight ----------------------------------
__global__ __launch_bounds__(256) void unfold_qk(const fp16_t* __restrict__ b1,
                                                 const fp16_t* __restrict__ b3,
                                                 fp16_t* __restrict__ qb,
                                                 fp16_t* __restrict__ kb,
                                                 const int* __restrict__ tab)
{
  int tid = threadIdx.x;
  int lb = blockIdx.z >> 1, sel = blockIdx.z & 1;
  const fp16_t* src = (sel ? b3 : b1) + (size_t)lb * 16 * HW_;
  fp16_t* dst       = (sel ? kb : qb) + (size_t)lb * NPIX * KQ;
  int i0 = blockIdx.y, i1 = i0 + 2048;
  int oy0 = i0 >> 6, ox0 = i0 & 63;
  int oy1 = i1 >> 6, ox1 = i1 & 63;
  int pb0 = oy0 * 1024 + ox0 * 4;
  int pb1 = oy1 * 1024 + ox1 * 4;
  int t[4];
#pragma unroll
  for (int u = 0; u < 4; ++u) t[u] = tab[tid + u * 256];
  fp16_t v0[4], v1[4];
#pragma unroll
  for (int u = 0; u < 4; ++u) {
    int off = (t[u] & 0xFFFFF) - 257;
    int ki  = (t[u] >> 20) & 15;
    int kj  = (t[u] >> 24) & 15;
    int vld = t[u] >> 28;
    int y0 = oy0 * 4 + ki - 1, x0 = ox0 * 4 + kj - 1;
    int y1 = oy1 * 4 + ki - 1, x1 = ox1 * 4 + kj - 1;
    v0[u] = (vld && (unsigned)y0 < 256u && (unsigned)x0 < 256u)
            ? src[pb0 + off] : (fp16_t)0.f;
    v1[u] = (vld && (unsigned)y1 < 256u && (unsigned)x1 < 256u)
            ? src[pb1 + off] : (fp16_t)0.f;
  }
#pragma unroll
  for (int u = 0; u < 4; ++u) {
    int kk = tid + u * 256;
    if (kk < KQ) {
      dst[(size_t)i0 * KQ + kk] = v0[u];
      dst[(size_t)i1 * KQ + kk] = v1[u];
    }
  }
}

// ------- v unfold, table-driven (wave-uniform row decode), 4 gathers in flight -------------
__global__ __launch_bounds__(256) void unfold_v(const bf16_t* __restrict__ src,
                                                bf16_t* __restrict__ vb,
                                                const int* __restrict__ tab)
{
  int tid = threadIdx.x;
  int p  = blockIdx.y;
  int lb = blockIdx.z;
  src += (size_t)lb * 16 * HW_;
  vb  += (size_t)lb * NPV * 4096;
  int t = tab[p];                       // wave-uniform -> scalar load
  int off = (t & 0xFFFFF) - 257;
  int ki  = (t >> 20) & 15;
  int kj  = (t >> 24) & 15;
  int vld = t >> 28;
  int jb = blockIdx.x * 1024 + tid;
  bf16_t v[4];
#pragma unroll
  for (int u = 0; u < 4; ++u) {
    int j = jb + u * 256;
    int oy = j >> 6, ox = j & 63;
    int y = oy * 4 + ki - 1, x = ox * 4 + kj - 1;
    v[u] = (vld && (unsigned)y < 256u && (unsigned)x < 256u)
           ? src[oy * 1024 + ox * 4 + off] : (bf16_t)0.f;
  }
#pragma unroll
  for (int u = 0; u < 4; ++u)
    vb[(size_t)p * 4096 + jb + u * 256] = v[u];
}

// ---------------- 256x256-tile GEMM, 8-phase, batched: C = alpha*A*B^T ---------------------
// (round-6 known-good schedule) + generalized batch/split decode:
//   u = swz/bps -> (bat = u/nspl, spl = u%nspl); tile = swz%bps -> (bm,bn).
//   A += bat*abat + spl*kofs; B += bat*bbat + spl*kofs; C += bat*cbat + spl*csplit.
// REQUIRES: K % 64 == 0, T = K/64 >= 3; gridDim.x = nbat*nspl*bps.
template <typename T, typename OT>
__global__ __launch_bounds__(512, 2) void gemm256(
    const T* __restrict__ A, int lda,
    const T* __restrict__ B, int ldb,
    OT* __restrict__ C, int ldc,
    int nbn, int bps, size_t csplit, int K, int kofs, float alpha,
    int nspl, size_t abat, size_t bbat, size_t cbat)
{
  using v8t = typename vec8<T>::t;
  __shared__ __align__(16) T lds[8][8192];   // 8 half-slots x 16 KiB = 128 KiB

  int nwg = gridDim.x, wg = blockIdx.x;
  int swz = ((nwg & 7) == 0) ? ((wg & 7) * (nwg >> 3) + (wg >> 3)) : wg;
  int u   = swz / bps;
  int rem = swz - u * bps;
  int bat = u / nspl, spl = u - bat * nspl;
  int bm  = rem / nbn, bn = rem - bm * nbn;
  A += (size_t)bat * abat + (size_t)spl * (size_t)kofs;
  B += (size_t)bat * bbat + (size_t)spl * (size_t)kofs;
  C += (size_t)bat * cbat + (size_t)spl * csplit;

  int tid  = threadIdx.x;
  int lane = tid & 63;
  int wid  = tid >> 6;
  int wr   = wid >> 2, wc = wid & 3;        // wave -> 128-row x 64-col output block
  int l16  = lane & 15;

  const T* gA = A + (size_t)(bm * 256 + (tid & 255)) * lda + (tid >> 8) * 8;
  const T* gB = B + (size_t)(bn * 256 + (tid & 255)) * ldb + (tid >> 8) * 8;

#define STAGE(gsrc, koffe, slot) {                                   \
    const T* _s = (gsrc) + (koffe);                                  \
    g2l16(_s,      &lds[slot][(size_t)tid * 8]);                     \
    g2l16(_s + 16, &lds[slot][(size_t)(512 + tid) * 8]); }

  int aoff = ((lane >> 4) * 256 + wr * 128 + l16) * 8;
  int boff = ((lane >> 4) * 256 + wc * 64 + l16) * 8;

  f32x4 acc[8][4];
#pragma unroll
  for (int f = 0; f < 8; ++f)
#pragma unroll
    for (int q = 0; q < 4; ++q) acc[f][q] = f32x4{0.f, 0.f, 0.f, 0.f};

  int T_ = K >> 6;   // BK = 64

  // prologue: 7 halves in steady-state order
  STAGE(gB, 0, 1)        // Bk0(0)
  STAGE(gA, 0, 0)        // Ak0(0)
  STAGE(gB, 32, 3)       // Bk1(0)
  STAGE(gA, 32, 2)       // Ak1(0)
  STAGE(gB, 64, 5)       // Bk0(1)
  STAGE(gA, 64, 4)       // Ak0(1)
  STAGE(gB, 96, 7)       // Bk1(1)
  asm volatile("s_waitcnt vmcnt(6)" ::: "memory");   // tile 0 fully resident
  __builtin_amdgcn_s_barrier();

  for (int t = 0; t < T_; ++t) {
    int pi = (t & 1) * 4;          // current tile's slot base
    int po = ((t + 1) & 1) * 4;    // other parity
    const T* sAk0 = &lds[pi + 0][0];
    const T* sBk0 = &lds[pi + 1][0];
    const T* sAk1 = &lds[pi + 2][0];
    const T* sBk1 = &lds[pi + 3][0];
    v8t bg[4], af[4];

    // ---- phase 0: read B(ks0) + A(ks0, rf0-3) | stage Ak1(t+1) | MFMA q0 ----
#pragma unroll
    for (int q = 0; q < 4; ++q) bg[q] = *(const v8t*)(sBk0 + boff + q * 128);
#pragma unroll
    for (int f = 0; f < 4; ++f) af[f] = *(const v8t*)(sAk0 + aoff + f * 128);
    if (t + 1 < T_) STAGE(gA, (t + 1) * 64 + 32, po + 2)
    __builtin_amdgcn_s_barrier();
    asm volatile("s_waitcnt lgkmcnt(0)" ::: "memory");
    __builtin_amdgcn_sched_barrier(0);
    __builtin_amdgcn_s_setprio(1);
#pragma unroll
    for (int f = 0; f < 4; ++f)
#pragma unroll
      for (int q = 0; q < 4; ++q)
        acc[f][q] = mfma16(af[f], bg[q], acc[f][q]);
    __builtin_amdgcn_s_setprio(0);
    __builtin_amdgcn_s_barrier();

    // ---- phase 1: read A(ks0, rf4-7) | stage Bk0(t+2) | MFMA q1 ----
#pragma unroll
    for (int f = 0; f < 4; ++f) af[f] = *(const v8t*)(sAk0 + aoff + 512 + f * 128);
    if (t + 2 < T_) STAGE(gB, (t + 2) * 64, pi + 1)
    __builtin_amdgcn_s_barrier();
    asm volatile("s_waitcnt lgkmcnt(0)" ::: "memory");
    __builtin_amdgcn_sched_barrier(0);
    __builtin_amdgcn_s_setprio(1);
#pragma unroll
    for (int f = 0; f < 4; ++f)
#pragma unroll
      for (int q = 0; q < 4; ++q)
        acc[4 + f][q] = mfma16(af[f], bg[q], acc[4 + f][q]);
    __builtin_amdgcn_s_setprio(0);
    __builtin_amdgcn_s_barrier();

    // ---- phase 2: read B(ks1) + A(ks1, rf0-3) | stage Ak0(t+2) | MFMA q2 ----
#pragma unroll
    for (int q = 0; q < 4; ++q) bg[q] = *(const v8t*)(sBk1 + boff + q * 128);
#pragma unroll
    for (int f = 0; f < 4; ++f) af[f] = *(const v8t*)(sAk1 + aoff + f * 128);
    if (t + 2 < T_) STAGE(gA, (t + 2) * 64, pi + 0)
    __builtin_amdgcn_s_barrier();
    asm volatile("s_waitcnt lgkmcnt(0)" ::: "memory");
    __builtin_amdgcn_sched_barrier(0);
    __builtin_amdgcn_s_setprio(1);
#pragma unroll
    for (int f = 0; f < 4; ++f)
#pragma unroll
      for (int q = 0; q < 4; ++q)
        acc[f][q] = mfma16(af[f], bg[q], acc[f][q]);
    __builtin_amdgcn_s_setprio(0);
    __builtin_amdgcn_s_barrier();

    // ---- phase 3: read A(ks1, rf4-7) | stage Bk1(t+2) | MFMA q3 | boundary vmcnt ----
#pragma unroll
    for (int f = 0; f < 4; ++f) af[f] = *(const v8t*)(sAk1 + aoff + 512 + f * 128);
    if (t + 2 < T_) STAGE(gB, (t + 2) * 64 + 32, pi + 3)
    __builtin_amdgcn_s_barrier();
    asm volatile("s_waitcnt lgkmcnt(0)" ::: "memory");
    __builtin_amdgcn_sched_barrier(0);
    __builtin_amdgcn_s_setprio(1);
#pragma unroll
    for (int f = 0; f < 4; ++f)
#pragma unroll
      for (int q = 0; q < 4; ++q)
        acc[4 + f][q] = mfma16(af[f], bg[q], acc[4 + f][q]);
    __builtin_amdgcn_s_setprio(0);
    if (t < T_ - 2)       { asm volatile("s_waitcnt vmcnt(6)" ::: "memory"); }
    else if (t == T_ - 2) { asm volatile("s_waitcnt vmcnt(0)" ::: "memory"); }
    __builtin_amdgcn_s_barrier();
  }
#undef STAGE

  // C/D layout: col = lane&15, row = (lane>>4)*4 + reg ; frag rows = wr*128 + F*16
  int r0 = bm * 256 + wr * 128 + (lane >> 4) * 4;
  int c0 = bn * 256 + wc * 64 + l16;
#pragma unroll
  for (int f = 0; f < 8; ++f)
#pragma unroll
    for (int q = 0; q < 4; ++q) {
      OT* cp = C + (size_t)(r0 + f * 16) * ldc + c0 + q * 16;
#pragma unroll
      for (int r = 0; r < 4; ++r) cp[(size_t)r * ldc] = (OT)(alpha * acc[f][q][r]);
    }
}

// ---------------- fused row softmax (batched over blockIdx.y) ----------------
__global__ __launch_bounds__(256) void softmax_rows(const float* __restrict__ S,
                                                    bf16_t* __restrict__ Att)
{
  S   += (size_t)blockIdx.y * NPIX * 4096;
  Att += (size_t)blockIdx.y * NPIX * 4096;
  int row = blockIdx.x;
  int tid = threadIdx.x;
  int lane = tid & 63, wid = tid >> 6;
  const float4* Sp = (const float4*)(S + (size_t)row * 4096);
  float4 vv[4];
  float m = -3.4e38f;
#pragma unroll
  for (int u = 0; u < 4; ++u) {
    vv[u] = Sp[u * 256 + tid];
    m = fmaxf(m, fmaxf(fmaxf(vv[u].x, vv[u].y), fmaxf(vv[u].z, vv[u].w)));
  }
#pragma unroll
  for (int off = 32; off; off >>= 1) m = fmaxf(m, __shfl_xor(m, off));
  __shared__ float redm[4], reds[4];
  if (lane == 0) redm[wid] = m;
  __syncthreads();
  m = fmaxf(fmaxf(redm[0], redm[1]), fmaxf(redm[2], redm[3]));
  float ssum = 0.f;
#pragma unroll
  for (int u = 0; u < 4; ++u) {
    vv[u].x = __expf(vv[u].x - m); vv[u].y = __expf(vv[u].y - m);
    vv[u].z = __expf(vv[u].z - m); vv[u].w = __expf(vv[u].w - m);
    ssum += vv[u].x + vv[u].y + vv[u].z + vv[u].w;
  }
#pragma unroll
  for (int off = 32; off; off >>= 1) ssum += __shfl_xor(ssum, off);
  if (lane == 0) reds[wid] = ssum;
  __syncthreads();
  float inv = 1.0f / (reds[0] + reds[1] + reds[2] + reds[3]);
  ushort4* Ap = (ushort4*)(Att + (size_t)row * 4096);
#pragma unroll
  for (int u = 0; u < 4; ++u) {
    union { bf16_t b[4]; ushort4 q; } pk;
    pk.b[0] = (bf16_t)(vv[u].x * inv);
    pk.b[1] = (bf16_t)(vv[u].y * inv);
    pk.b[2] = (bf16_t)(vv[u].z * inv);
    pk.b[3] = (bf16_t)(vv[u].w * inv);
    Ap[u * 256 + tid] = pk.q;
  }
}

// ---------------- split-K reduce (batched over blockIdx.y; slot stride = 4*4096*1024) ------
__global__ __launch_bounds__(256) void reduce4(const bf16_t* __restrict__ part,
                                               float* __restrict__ amv)
{
  part += (size_t)blockIdx.y * 4 * 4096 * 1024;   // matches gemm2 cbat exactly
  amv  += (size_t)blockIdx.y * 4096 * 1024;
  size_t i = ((size_t)blockIdx.x * 256 + threadIdx.x) * 8;   // over 4096*1024 elems
  const size_t S = (size_t)4096 * 1024;
  bf16x8 a = *(const bf16x8*)(part + i);
  bf16x8 b = *(const bf16x8*)(part + i + S);
  bf16x8 c = *(const bf16x8*)(part + i + 2 * S);
  bf16x8 d = *(const bf16x8*)(part + i + 3 * S);
  float o[8];
#pragma unroll
  for (int j = 0; j < 8; ++j)
    o[j] = (float)a[j] + (float)b[j] + (float)c[j] + (float)d[j];
  float4* op = (float4*)(amv + i);
  op[0] = float4{o[0], o[1], o[2], o[3]};
  op[1] = float4{o[4], o[5], o[6], o[7]};
}

// ---------------- fold + mask normalize (batched over blockIdx.y) ----------------
__global__ __launch_bounds__(256) void fold_norm(const float* __restrict__ amv,
                                                 float* __restrict__ zi)
{
  amv += (size_t)blockIdx.y * 4096 * 1024;
  zi  += (size_t)blockIdx.y * 16 * HW_;
  int idx = blockIdx.x * 256 + threadIdx.x;   // c*65536 + h*256 + w
  int c = idx >> 16;
  int h = (idx >> 8) & 255;
  int w = idx & 255;
  int t = h + 3, u = w + 3;
  int oy0 = (t - 3) >> 2, oy1 = min(63, t >> 2);
  int ox0 = (u - 3) >> 2, ox1 = min(63, u >> 2);
  float sum = 0.f;
  for (int oy = oy0; oy <= oy1; ++oy) {
    int ki = t - oy * 4;
    for (int ox = ox0; ox <= ox1; ++ox) {
      int kj = u - ox * 4;
      sum += amv[(size_t)(oy * 64 + ox) * NPV + c * 49 + ki * 7 + kj];
    }
  }
  int cnt = (oy1 - oy0 + 1) * (ox1 - ox0 + 1);
  zi[idx] = sum / (float)cnt;
}

// ---------------- final conv (batched over blockIdx.y) ----------------
__global__ __launch_bounds__(256) void out_conv(const float* __restrict__ zi,
                                                const float* __restrict__ bo,
                                                const float* __restrict__ ww,
                                                const float* __restrict__ wb,
                                                float* __restrict__ outb)
{
  zi   += (size_t)blockIdx.y * 16 * HW_;
  bo   += (size_t)blockIdx.y * 64 * HW_;
  outb += (size_t)blockIdx.y * 64 * HW_;
  __shared__ float wws[1024], wbs[64];
  int tid = threadIdx.x;
  for (int i = tid; i < 1024; i += 256) wws[i] = ww[i];
  if (tid < 64) wbs[tid] = wb[tid];
  __syncthreads();
  int hw = blockIdx.x * 256 + tid;
  float z[16];
#pragma unroll
  for (int c = 0; c < 16; ++c) z[c] = zi[(size_t)c * HW_ + hw];
  for (int o = 0; o < 64; ++o) {
    float a = wbs[o];
#pragma unroll
    for (int c = 0; c < 16; ++c) a = fmaf(wws[o * 16 + c], z[c], a);
    outb[(size_t)o * HW_ + hw] = bo[(size_t)o * HW_ + hw] + a;
  }
}

// ---------------- host orchestration ----------------
static inline size_t alup(size_t x) { return (x + 255) & ~(size_t)255; }

extern "C" void kernel_launch(void* const* d_in, const int* in_sizes, int n_in,
                              void* d_out, int out_size, void* d_ws, size_t ws_size,
                              hipStream_t stream) {
  const float* s   = (const float*)d_in[0];
  const float* g   = (const float*)d_in[1];
  const float* g_w = (const float*)d_in[2];
  const float* g_b = (const float*)d_in[3];
  const float* t_w = (const float*)d_in[4];
  const float* t_b = (const float*)d_in[5];
  const float* p_w = (const float*)d_in[6];
  const float* p_b = (const float*)d_in[7];
  const float* w_w = (const float*)d_in[8];
  const float* w_b = (const float*)d_in[9];
  float* out = (float*)d_out;

  const size_t szB1 = (size_t)16 * HW_ * 2;          // fp16/bf16 conv outs (per batch)
  const size_t szQK = (size_t)NPIX * KQ * 2;         // per batch
  const size_t szV  = (size_t)NPV * 4096 * 2;        // per batch
  const size_t szSc = (size_t)NPIX * 4096 * 4;       // per chain slot (f32); part aliases
  const size_t szAtt = (size_t)NPIX * 4096 * 2;
  const size_t szZi  = (size_t)16 * HW_ * 4;
  const size_t szAmv = (size_t)NPIX * NPV * 4;
  const size_t szTab = (size_t)1024 * 4;

  // choose largest G in {8,4,2,1}; chain depth CD = 2 when G >= 2
  int G = 1;
  for (int cand = 8; cand >= 1; cand >>= 1) {
    int cd = cand >= 2 ? 2 : 1;
    size_t need = alup(szB1) * 3 * cand + alup(szQK) * 2 * cand + alup(szV) * cand
                + (size_t)cd * (alup(szSc) + alup(szAtt) + alup(szZi) + alup(szAmv))
                + alup(szTab);
    if (need <= ws_size) { G = cand; break; }
  }
  int CD = G >= 2 ? 2 : 1;

  uint8_t* wp = (uint8_t*)d_ws;
  fp16_t* b1    = (fp16_t*)wp; wp += alup(szB1) * G;
  bf16_t* b2    = (bf16_t*)wp; wp += alup(szB1) * G;
  fp16_t* b3    = (fp16_t*)wp; wp += alup(szB1) * G;
  fp16_t* qbuf  = (fp16_t*)wp; wp += alup(szQK) * G;
  fp16_t* kbuf  = (fp16_t*)wp; wp += alup(szQK) * G;
  bf16_t* vbufp = (bf16_t*)wp; wp += alup(szV) * G;
  float*  score = (float*)wp;  wp += alup(szSc) * CD;   // contiguous CD slots
  bf16_t* att   = (bf16_t*)wp; wp += alup(szAtt) * CD;
  float*  zi    = (float*)wp;  wp += alup(szZi) * CD;
  float*  amv   = (float*)wp;  wp += alup(szAmv) * CD;
  int*    tab   = (int*)wp;    wp += alup(szTab);
  bf16_t* part  = (bf16_t*)score;   // CD compact 32MiB part slots inside score region

  // slot strides in ELEMENTS (alup is identity here: all sizes are 256-multiples)
  const size_t SCS  = szSc / 4;                 // score slot stride (f32) = NPIX*4096
  const size_t ATTS = szAtt / 2;                // att slot stride (bf16) = NPIX*4096
  const size_t QKS  = (size_t)NPIX * KQ;
  const size_t VBS  = (size_t)NPV * 4096;
  const size_t PARTSLOT = (size_t)4 * 4096 * 1024;  // bf16 elems; 2 slots = 64MiB = score[0]

  build_tab<<<dim3(4), dim3(256), 0, stream>>>(tab);

  for (int g0 = 0; g0 < 8; g0 += G) {
    const float* boG = s + (size_t)g0 * 64 * HW_;
    const float* dgG = g + (size_t)g0 * 64 * HW_;

    conv1x1_3<<<dim3(384, G), dim3(256), 0, stream>>>(boG, dgG, g_w, g_b, t_w, t_b,
                                                      p_w, p_b, b1, b2, b3);
    unfold_qk<<<dim3(1, 2048, 2 * G), dim3(256), 0, stream>>>(b1, b3, qbuf, kbuf, tab);
    unfold_v <<<dim3(4, NPV, G),      dim3(256), 0, stream>>>(b2, vbufp, tab);

    for (int lb = 0; lb < G; lb += CD) {
      int cd = (G - lb >= CD) ? CD : 1;
      fp16_t* qb = qbuf + (size_t)lb * QKS;
      fp16_t* kb = kbuf + (size_t)lb * QKS;
      bf16_t* vb = vbufp + (size_t)lb * VBS;
      const float* bo = s + (size_t)(g0 + lb) * 64 * HW_;
      float* ob = out + (size_t)(g0 + lb) * 64 * HW_;

      // score[bat] = 10 * q[bat] k[bat]^T   (fp16, K=832, T=13)
      gemm256<fp16_t, float><<<dim3(256 * cd), dim3(512), 0, stream>>>(
          qb, KQ, kb, KQ, score, 4096,
          16, 256, (size_t)0, KQ, 0, 10.0f,
          1, QKS, QKS, SCS);
      softmax_rows<<<dim3(4096, cd), dim3(256), 0, stream>>>(score, att);
      // part[bat][spl] = att[bat][:, spl*1024+...] @ v[bat]^T  (split-K=4, bf16 partials)
      gemm256<bf16_t, bf16_t><<<dim3(256 * cd), dim3(512), 0, stream>>>(
          att, 4096, vb, 4096, part, 1024,
          4, 64, (size_t)4096 * 1024, 1024, 1024, 1.0f,
          4, ATTS, VBS, PARTSLOT);
      reduce4<<<dim3(2048, cd), dim3(256), 0, stream>>>(part, amv);
      fold_norm<<<dim3(4096, cd), dim3(256), 0, stream>>>(amv, zi);
      out_conv<<<dim3(256, cd), dim3(256), 0, stream>>>(zi, bo, w_w, w_b, ob);
    }
  }
}

// Round 21
// 1356.033 us; speedup vs baseline: 1.1165x; 1.0221x over previous
//
#include <hip/hip_runtime.h>
#include <cstdint>
#include <cstddef>

// ---------------- types ----------------
typedef __bf16 bf16_t;
typedef _Float16 fp16_t;
typedef bf16_t bf16x8 __attribute__((ext_vector_type(8)));
typedef fp16_t fp16x8 __attribute__((ext_vector_type(8)));
typedef bf16_t bf16x2 __attribute__((ext_vector_type(2)));
typedef fp16_t fp16x2 __attribute__((ext_vector_type(2)));
typedef float  f32x4  __attribute__((ext_vector_type(4)));
typedef float  f32x2  __attribute__((ext_vector_type(2)));

#define GAS __attribute__((address_space(1)))
#define LAS __attribute__((address_space(3)))

__device__ __forceinline__ void g2l16(const void* g, void* l) {
  // async global->LDS, 16B per lane; LDS dest is wave-uniform base + lane*16
  __builtin_amdgcn_global_load_lds((const GAS unsigned int*)g,
                                   (LAS unsigned int*)l, 16, 0, 0);
}

__device__ __forceinline__ f32x4 mfma16(bf16x8 a, bf16x8 b, f32x4 c) {
  return __builtin_amdgcn_mfma_f32_16x16x32_bf16(a, b, c, 0, 0, 0);
}
__device__ __forceinline__ f32x4 mfma16(fp16x8 a, fp16x8 b, f32x4 c) {
  return __builtin_amdgcn_mfma_f32_16x16x32_f16(a, b, c, 0, 0, 0);
}
template <typename T> struct vec8;
template <> struct vec8<bf16_t> { using t = bf16x8; };
template <> struct vec8<fp16_t> { using t = fp16x8; };

// Problem constants
#define HW_  65536      // 256*256
#define NPIX 4096       // 64*64 patch grid
#define KQ   832        // 784 real + pad to 832 (fp16 single-pass), 832 % 64 == 0
#define NPV  1024       // v rows padded to 1024 (784 real)

// ------- decode table: tab[kk] = (c*HW+(ki-1)*256+(kj-1)+257) | ki<<20 | kj<<24 | 1<<28 ----
__global__ void build_tab(int* __restrict__ tab) {
  int kk = blockIdx.x * 256 + threadIdx.x;
  int v = 0;
  if (kk < 784) {
    int c = kk / 49, r = kk - c * 49, ki = r / 7, kj = r - ki * 7;
    int off = c * HW_ + (ki - 1) * 256 + (kj - 1) + 257;   // biased, >=0, <2^20
    v = off | (ki << 20) | (kj << 24) | (1 << 28);
  }
  tab[kk] = v;
}

// ------- 1x1 convs, float2-vectorized; type in fastest grid dim --------------------------
__global__ __launch_bounds__(256) void conv1x1_3(
    const float* __restrict__ bo, const float* __restrict__ dg,
    const float* __restrict__ gw, const float* __restrict__ gb,
    const float* __restrict__ tw, const float* __restrict__ tb,
    const float* __restrict__ pw, const float* __restrict__ pb,
    fp16_t* __restrict__ b1, bf16_t* __restrict__ b2, fp16_t* __restrict__ b3)
{
  __shared__ float wS[1024], bia[16];
  int tid  = threadIdx.x;
  int lb   = blockIdx.y;
  int z    = blockIdx.x % 3;
  int xblk = blockIdx.x / 3;
  const float* w   = (z == 0) ? gw : (z == 1) ? tw : pw;
  const float* bb  = (z == 0) ? gb : (z == 1) ? tb : pb;
  const float* src = ((z == 0) ? bo : dg) + (size_t)lb * 64 * HW_;
  for (int i = tid; i < 1024; i += 256) wS[i] = w[i];
  if (tid < 16) bia[tid] = bb[tid];
  __syncthreads();

  size_t hw = ((size_t)xblk * 256 + tid) * 2;
  f32x2 acc[16];
#pragma unroll
  for (int o = 0; o < 16; ++o) {
    float bv = bia[o];
    acc[o] = f32x2{bv, bv};
  }
  for (int c = 0; c < 64; c += 8) {
    float2 v[8];
#pragma unroll
    for (int u = 0; u < 8; ++u)
      v[u] = *(const float2*)(src + (size_t)(c + u) * HW_ + hw);
#pragma unroll
    for (int u = 0; u < 8; ++u)
#pragma unroll
      for (int o = 0; o < 16; ++o) {
        float wv = wS[o * 64 + c + u];
        acc[o][0] = fmaf(wv, v[u].x, acc[o][0]);
        acc[o][1] = fmaf(wv, v[u].y, acc[o][1]);
      }
  }
  if (z == 1) {
    bf16_t* dst = b2 + (size_t)lb * 16 * HW_;
#pragma unroll
    for (int o = 0; o < 16; ++o) {
      bf16x2 pk;
      pk[0] = (bf16_t)acc[o][0];
      pk[1] = (bf16_t)acc[o][1];
      *(bf16x2*)(dst + (size_t)o * HW_ + hw) = pk;
    }
  } else {
    fp16_t* dst = ((z == 0) ? b1 : b3) + (size_t)lb * 16 * HW_;
#pragma unroll
    for (int o = 0; o < 16; ++o) {
      fp16x2 pk;
      pk[0] = (fp16_t)acc[o][0];
      pk[1] = (fp16_t)acc[o][1];
      *(fp16x2*)(dst + (size_t)o * HW_ + hw) = pk;
    }
  }
}

// ------- unfold q & k, table-driven, 8 gathers in flight ----------------------------------
__global__ __launch_bounds__(256) void unfold_qk(const fp16_t* __restrict__ b1,
                                                 const fp16_t* __restrict__ b3,
                                                 fp16_t* __restrict__ qb,
                                                 fp16_t* __restrict__ kb,
                                                 const int* __restrict__ tab)
{
  int tid = threadIdx.x;
  int lb = blockIdx.z >> 1, sel = blockIdx.z & 1;
  const fp16_t* src = (sel ? b3 : b1) + (size_t)lb * 16 * HW_;
  fp16_t* dst       = (sel ? kb : qb) + (size_t)lb * NPIX * KQ;
  int i0 = blockIdx.y, i1 = i0 + 2048;
  int oy0 = i0 >> 6, ox0 = i0 & 63;
  int oy1 = i1 >> 6, ox1 = i1 & 63;
  int pb0 = oy0 * 1024 + ox0 * 4;
  int pb1 = oy1 * 1024 + ox1 * 4;
  int t[4];
#pragma unroll
  for (int u = 0; u < 4; ++u) t[u] = tab[tid + u * 256];
  fp16_t v0[4], v1[4];
#pragma unroll
  for (int u = 0; u < 4; ++u) {
    int off = (t[u] & 0xFFFFF) - 257;
    int ki  = (t[u] >> 20) & 15;
    int kj  = (t[u] >> 24) & 15;
    int vld = t[u] >> 28;
    int y0 = oy0 * 4 + ki - 1, x0 = ox0 * 4 + kj - 1;
    int y1 = oy1 * 4 + ki - 1, x1 = ox1 * 4 + kj - 1;
    v0[u] = (vld && (unsigned)y0 < 256u && (unsigned)x0 < 256u)
            ? src[pb0 + off] : (fp16_t)0.f;
    v1[u] = (vld && (unsigned)y1 < 256u && (unsigned)x1 < 256u)
            ? src[pb1 + off] : (fp16_t)0.f;
  }
#pragma unroll
  for (int u = 0; u < 4; ++u) {
    int kk = tid + u * 256;
    if (kk < KQ) {
      dst[(size_t)i0 * KQ + kk] = v0[u];
      dst[(size_t)i1 * KQ + kk] = v1[u];
    }
  }
}

// ------- v unfold, table-driven (wave-uniform row decode), 4 gathers in flight -------------
__global__ __launch_bounds__(256) void unfold_v(const bf16_t* __restrict__ src,
                                                bf16_t* __restrict__ vb,
                                                const int* __restrict__ tab)
{
  int tid = threadIdx.x;
  int p  = blockIdx.y;
  int lb = blockIdx.z;
  src += (size_t)lb * 16 * HW_;
  vb  += (size_t)lb * NPV * 4096;
  int t = tab[p];                       // wave-uniform -> scalar load
  int off = (t & 0xFFFFF) - 257;
  int ki  = (t >> 20) & 15;
  int kj  = (t >> 24) & 15;
  int vld = t >> 28;
  int jb = blockIdx.x * 1024 + tid;
  bf16_t v[4];
#pragma unroll
  for (int u = 0; u < 4; ++u) {
    int j = jb + u * 256;
    int oy = j >> 6, ox = j & 63;
    int y = oy * 4 + ki - 1, x = ox * 4 + kj - 1;
    v[u] = (vld && (unsigned)y < 256u && (unsigned)x < 256u)
           ? src[oy * 1024 + ox * 4 + off] : (bf16_t)0.f;
  }
#pragma unroll
  for (int u = 0; u < 4; ++u)
    vb[(size_t)p * 4096 + jb + u * 256] = v[u];
}

// ---------------- 256x256-tile GEMM, 8-phase, batched: C = alpha*A*B^T ---------------------
// u = swz/bps -> (bat = u/nspl, spl = u%nspl); tile = swz%bps -> (bm,bn).
// REQUIRES: K % 64 == 0, T = K/64 >= 3; gridDim.x = nbat*nspl*bps.
template <typename T, typename OT>
__global__ __launch_bounds__(512, 2) void gemm256(
    const T* __restrict__ A, int lda,
    const T* __restrict__ B, int ldb,
    OT* __restrict__ C, int ldc,
    int nbn, int bps, size_t csplit, int K, int kofs, float alpha,
    int nspl, size_t abat, size_t bbat, size_t cbat)
{
  using v8t = typename vec8<T>::t;
  __shared__ __align__(16) T lds[8][8192];   // 8 half-slots x 16 KiB = 128 KiB

  int nwg = gridDim.x, wg = blockIdx.x;
  int swz = ((nwg & 7) == 0) ? ((wg & 7) * (nwg >> 3) + (wg >> 3)) : wg;
  int u   = swz / bps;
  int rem = swz - u * bps;
  int bat = u / nspl, spl = u - bat * nspl;
  int bm  = rem / nbn, bn = rem - bm * nbn;
  A += (size_t)bat * abat + (size_t)spl * (size_t)kofs;
  B += (size_t)bat * bbat + (size_t)spl * (size_t)kofs;
  C += (size_t)bat * cbat + (size_t)spl * csplit;

  int tid  = threadIdx.x;
  int lane = tid & 63;
  int wid  = tid >> 6;
  int wr   = wid >> 2, wc = wid & 3;        // wave -> 128-row x 64-col output block
  int l16  = lane & 15;

  const T* gA = A + (size_t)(bm * 256 + (tid & 255)) * lda + (tid >> 8) * 8;
  const T* gB = B + (size_t)(bn * 256 + (tid & 255)) * ldb + (tid >> 8) * 8;

#define STAGE(gsrc, koffe, slot) {                                   \
    const T* _s = (gsrc) + (koffe);                                  \
    g2l16(_s,      &lds[slot][(size_t)tid * 8]);                     \
    g2l16(_s + 16, &lds[slot][(size_t)(512 + tid) * 8]); }

  int aoff = ((lane >> 4) * 256 + wr * 128 + l16) * 8;
  int boff = ((lane >> 4) * 256 + wc * 64 + l16) * 8;

  f32x4 acc[8][4];
#pragma unroll
  for (int f = 0; f < 8; ++f)
#pragma unroll
    for (int q = 0; q < 4; ++q) acc[f][q] = f32x4{0.f, 0.f, 0.f, 0.f};

  int T_ = K >> 6;   // BK = 64

  // prologue: 7 halves in steady-state order
  STAGE(gB, 0, 1)        // Bk0(0)
  STAGE(gA, 0, 0)        // Ak0(0)
  STAGE(gB, 32, 3)       // Bk1(0)
  STAGE(gA, 32, 2)       // Ak1(0)
  STAGE(gB, 64, 5)       // Bk0(1)
  STAGE(gA, 64, 4)       // Ak0(1)
  STAGE(gB, 96, 7)       // Bk1(1)
  asm volatile("s_waitcnt vmcnt(6)" ::: "memory");   // tile 0 fully resident
  __builtin_amdgcn_s_barrier();

  for (int t = 0; t < T_; ++t) {
    int pi = (t & 1) * 4;          // current tile's slot base
    int po = ((t + 1) & 1) * 4;    // other parity
    const T* sAk0 = &lds[pi + 0][0];
    const T* sBk0 = &lds[pi + 1][0];
    const T* sAk1 = &lds[pi + 2][0];
    const T* sBk1 = &lds[pi + 3][0];
    v8t bg[4], af[4];

    // ---- phase 0: read B(ks0) + A(ks0, rf0-3) | stage Ak1(t+1) | MFMA q0 ----
#pragma unroll
    for (int q = 0; q < 4; ++q) bg[q] = *(const v8t*)(sBk0 + boff + q * 128);
#pragma unroll
    for (int f = 0; f < 4; ++f) af[f] = *(const v8t*)(sAk0 + aoff + f * 128);
    if (t + 1 < T_) STAGE(gA, (t + 1) * 64 + 32, po + 2)
    __builtin_amdgcn_s_barrier();
    asm volatile("s_waitcnt lgkmcnt(0)" ::: "memory");
    __builtin_amdgcn_sched_barrier(0);
    __builtin_amdgcn_s_setprio(1);
#pragma unroll
    for (int f = 0; f < 4; ++f)
#pragma unroll
      for (int q = 0; q < 4; ++q)
        acc[f][q] = mfma16(af[f], bg[q], acc[f][q]);
    __builtin_amdgcn_s_setprio(0);
    __builtin_amdgcn_s_barrier();

    // ---- phase 1: read A(ks0, rf4-7) | stage Bk0(t+2) | MFMA q1 ----
#pragma unroll
    for (int f = 0; f < 4; ++f) af[f] = *(const v8t*)(sAk0 + aoff + 512 + f * 128);
    if (t + 2 < T_) STAGE(gB, (t + 2) * 64, pi + 1)
    __builtin_amdgcn_s_barrier();
    asm volatile("s_waitcnt lgkmcnt(0)" ::: "memory");
    __builtin_amdgcn_sched_barrier(0);
    __builtin_amdgcn_s_setprio(1);
#pragma unroll
    for (int f = 0; f < 4; ++f)
#pragma unroll
      for (int q = 0; q < 4; ++q)
        acc[4 + f][q] = mfma16(af[f], bg[q], acc[4 + f][q]);
    __builtin_amdgcn_s_setprio(0);
    __builtin_amdgcn_s_barrier();

    // ---- phase 2: read B(ks1) + A(ks1, rf0-3) | stage Ak0(t+2) | MFMA q2 ----
#pragma unroll
    for (int q = 0; q < 4; ++q) bg[q] = *(const v8t*)(sBk1 + boff + q * 128);
#pragma unroll
    for (int f = 0; f < 4; ++f) af[f] = *(const v8t*)(sAk1 + aoff + f * 128);
    if (t + 2 < T_) STAGE(gA, (t + 2) * 64, pi + 0)
    __builtin_amdgcn_s_barrier();
    asm volatile("s_waitcnt lgkmcnt(0)" ::: "memory");
    __builtin_amdgcn_sched_barrier(0);
    __builtin_amdgcn_s_setprio(1);
#pragma unroll
    for (int f = 0; f < 4; ++f)
#pragma unroll
      for (int q = 0; q < 4; ++q)
        acc[f][q] = mfma16(af[f], bg[q], acc[f][q]);
    __builtin_amdgcn_s_setprio(0);
    __builtin_amdgcn_s_barrier();

    // ---- phase 3: read A(ks1, rf4-7) | stage Bk1(t+2) | MFMA q3 | boundary vmcnt ----
#pragma unroll
    for (int f = 0; f < 4; ++f) af[f] = *(const v8t*)(sAk1 + aoff + 512 + f * 128);
    if (t + 2 < T_) STAGE(gB, (t + 2) * 64 + 32, pi + 3)
    __builtin_amdgcn_s_barrier();
    asm volatile("s_waitcnt lgkmcnt(0)" ::: "memory");
    __builtin_amdgcn_sched_barrier(0);
    __builtin_amdgcn_s_setprio(1);
#pragma unroll
    for (int f = 0; f < 4; ++f)
#pragma unroll
      for (int q = 0; q < 4; ++q)
        acc[4 + f][q] = mfma16(af[f], bg[q], acc[4 + f][q]);
    __builtin_amdgcn_s_setprio(0);
    if (t < T_ - 2)       { asm volatile("s_waitcnt vmcnt(6)" ::: "memory"); }
    else if (t == T_ - 2) { asm volatile("s_waitcnt vmcnt(0)" ::: "memory"); }
    __builtin_amdgcn_s_barrier();
  }
#undef STAGE

  // C/D layout: col = lane&15, row = (lane>>4)*4 + reg ; frag rows = wr*128 + F*16
  int r0 = bm * 256 + wr * 128 + (lane >> 4) * 4;
  int c0 = bn * 256 + wc * 64 + l16;
#pragma unroll
  for (int f = 0; f < 8; ++f)
#pragma unroll
    for (int q = 0; q < 4; ++q) {
      OT* cp = C + (size_t)(r0 + f * 16) * ldc + c0 + q * 16;
#pragma unroll
      for (int r = 0; r < 4; ++r) cp[(size_t)r * ldc] = (OT)(alpha * acc[f][q][r]);
    }
}

// ---------------- fused row softmax (batched over blockIdx.y) ----------------
__global__ __launch_bounds__(256) void softmax_rows(const float* __restrict__ S,
                                                    bf16_t* __restrict__ Att)
{
  S   += (size_t)blockIdx.y * NPIX * 4096;
  Att += (size_t)blockIdx.y * NPIX * 4096;
  int row = blockIdx.x;
  int tid = threadIdx.x;
  int lane = tid & 63, wid = tid >> 6;
  const float4* Sp = (const float4*)(S + (size_t)row * 4096);
  float4 vv[4];
  float m = -3.4e38f;
#pragma unroll
  for (int u = 0; u < 4; ++u) {
    vv[u] = Sp[u * 256 + tid];
    m = fmaxf(m, fmaxf(fmaxf(vv[u].x, vv[u].y), fmaxf(vv[u].z, vv[u].w)));
  }
#pragma unroll
  for (int off = 32; off; off >>= 1) m = fmaxf(m, __shfl_xor(m, off));
  __shared__ float redm[4], reds[4];
  if (lane == 0) redm[wid] = m;
  __syncthreads();
  m = fmaxf(fmaxf(redm[0], redm[1]), fmaxf(redm[2], redm[3]));
  float ssum = 0.f;
#pragma unroll
  for (int u = 0; u < 4; ++u) {
    vv[u].x = __expf(vv[u].x - m); vv[u].y = __expf(vv[u].y - m);
    vv[u].z = __expf(vv[u].z - m); vv[u].w = __expf(vv[u].w - m);
    ssum += vv[u].x + vv[u].y + vv[u].z + vv[u].w;
  }
#pragma unroll
  for (int off = 32; off; off >>= 1) ssum += __shfl_xor(ssum, off);
  if (lane == 0) reds[wid] = ssum;
  __syncthreads();
  float inv = 1.0f / (reds[0] + reds[1] + reds[2] + reds[3]);
  ushort4* Ap = (ushort4*)(Att + (size_t)row * 4096);
#pragma unroll
  for (int u = 0; u < 4; ++u) {
    union { bf16_t b[4]; ushort4 q; } pk;
    pk.b[0] = (bf16_t)(vv[u].x * inv);
    pk.b[1] = (bf16_t)(vv[u].y * inv);
    pk.b[2] = (bf16_t)(vv[u].z * inv);
    pk.b[3] = (bf16_t)(vv[u].w * inv);
    Ap[u * 256 + tid] = pk.q;
  }
}

// ---------------- split-K=2 reduce (batched over blockIdx.y; slot stride 2*4096*1024) ------
__global__ __launch_bounds__(256) void reduce2(const bf16_t* __restrict__ part,
                                               float* __restrict__ amv)
{
  part += (size_t)blockIdx.y * 2 * 4096 * 1024;   // matches gemm2 cbat exactly
  amv  += (size_t)blockIdx.y * 4096 * 1024;
  size_t i = ((size_t)blockIdx.x * 256 + threadIdx.x) * 8;   // over 4096*1024 elems
  const size_t S = (size_t)4096 * 1024;
  bf16x8 a = *(const bf16x8*)(part + i);
  bf16x8 b = *(const bf16x8*)(part + i + S);
  float o[8];
#pragma unroll
  for (int j = 0; j < 8; ++j)
    o[j] = (float)a[j] + (float)b[j];
  float4* op = (float4*)(amv + i);
  op[0] = float4{o[0], o[1], o[2], o[3]};
  op[1] = float4{o[4], o[5], o[6], o[7]};
}

// ---------------- fold + mask normalize (batched over blockIdx.y) ----------------
__global__ __launch_bounds__(256) void fold_norm(const float* __restrict__ amv,
                                                 float* __restrict__ zi)
{
  amv += (size_t)blockIdx.y * 4096 * 1024;
  zi  += (size_t)blockIdx.y * 16 * HW_;
  int idx = blockIdx.x * 256 + threadIdx.x;   // c*65536 + h*256 + w
  int c = idx >> 16;
  int h = (idx >> 8) & 255;
  int w = idx & 255;
  int t = h + 3, u = w + 3;
  int oy0 = (t - 3) >> 2, oy1 = min(63, t >> 2);
  int ox0 = (u - 3) >> 2, ox1 = min(63, u >> 2);
  float sum = 0.f;
  for (int oy = oy0; oy <= oy1; ++oy) {
    int ki = t - oy * 4;
    for (int ox = ox0; ox <= ox1; ++ox) {
      int kj = u - ox * 4;
      sum += amv[(size_t)(oy * 64 + ox) * NPV + c * 49 + ki * 7 + kj];
    }
  }
  int cnt = (oy1 - oy0 + 1) * (ox1 - ox0 + 1);
  zi[idx] = sum / (float)cnt;
}

// ---------------- final conv (batched over blockIdx.y) ----------------
__global__ __launch_bounds__(256) void out_conv(const float* __restrict__ zi,
                                                const float* __restrict__ bo,
                                                const float* __restrict__ ww,
                                                const float* __restrict__ wb,
                                                float* __restrict__ outb)
{
  zi   += (size_t)blockIdx.y * 16 * HW_;
  bo   += (size_t)blockIdx.y * 64 * HW_;
  outb += (size_t)blockIdx.y * 64 * HW_;
  __shared__ float wws[1024], wbs[64];
  int tid = threadIdx.x;
  for (int i = tid; i < 1024; i += 256) wws[i] = ww[i];
  if (tid < 64) wbs[tid] = wb[tid];
  __syncthreads();
  int hw = blockIdx.x * 256 + tid;
  float z[16];
#pragma unroll
  for (int c = 0; c < 16; ++c) z[c] = zi[(size_t)c * HW_ + hw];
  for (int o = 0; o < 64; ++o) {
    float a = wbs[o];
#pragma unroll
    for (int c = 0; c < 16; ++c) a = fmaf(wws[o * 16 + c], z[c], a);
    outb[(size_t)o * HW_ + hw] = bo[(size_t)o * HW_ + hw] + a;
  }
}

// ---------------- host orchestration ----------------
static inline size_t alup(size_t x) { return (x + 255) & ~(size_t)255; }

extern "C" void kernel_launch(void* const* d_in, const int* in_sizes, int n_in,
                              void* d_out, int out_size, void* d_ws, size_t ws_size,
                              hipStream_t stream) {
  const float* s   = (const float*)d_in[0];
  const float* g   = (const float*)d_in[1];
  const float* g_w = (const float*)d_in[2];
  const float* g_b = (const float*)d_in[3];
  const float* t_w = (const float*)d_in[4];
  const float* t_b = (const float*)d_in[5];
  const float* p_w = (const float*)d_in[6];
  const float* p_b = (const float*)d_in[7];
  const float* w_w = (const float*)d_in[8];
  const float* w_b = (const float*)d_in[9];
  float* out = (float*)d_out;

  const size_t szB1 = (size_t)16 * HW_ * 2;          // fp16/bf16 conv outs (per batch)
  const size_t szQK = (size_t)NPIX * KQ * 2;         // per batch
  const size_t szV  = (size_t)NPV * 4096 * 2;        // per batch
  const size_t szSc = (size_t)NPIX * 4096 * 4;       // per chain slot (f32); part aliases
  const size_t szAtt = (size_t)NPIX * 4096 * 2;
  const size_t szZi  = (size_t)16 * HW_ * 4;
  const size_t szAmv = (size_t)NPIX * NPV * 4;
  const size_t szTab = (size_t)1024 * 4;

  // choose largest G in {8,4,2,1}; chain depth CD = 2 when G >= 2
  int G = 1;
  for (int cand = 8; cand >= 1; cand >>= 1) {
    int cd = cand >= 2 ? 2 : 1;
    size_t need = alup(szB1) * 3 * cand + alup(szQK) * 2 * cand + alup(szV) * cand
                + (size_t)cd * (alup(szSc) + alup(szAtt) + alup(szZi) + alup(szAmv))
                + alup(szTab);
    if (need <= ws_size) { G = cand; break; }
  }
  int CD = G >= 2 ? 2 : 1;

  uint8_t* wp = (uint8_t*)d_ws;
  fp16_t* b1    = (fp16_t*)wp; wp += alup(szB1) * G;
  bf16_t* b2    = (bf16_t*)wp; wp += alup(szB1) * G;
  fp16_t* b3    = (fp16_t*)wp; wp += alup(szB1) * G;
  fp16_t* qbuf  = (fp16_t*)wp; wp += alup(szQK) * G;
  fp16_t* kbuf  = (fp16_t*)wp; wp += alup(szQK) * G;
  bf16_t* vbufp = (bf16_t*)wp; wp += alup(szV) * G;
  float*  score = (float*)wp;  wp += alup(szSc) * CD;   // contiguous CD slots
  bf16_t* att   = (bf16_t*)wp; wp += alup(szAtt) * CD;
  float*  zi    = (float*)wp;  wp += alup(szZi) * CD;
  float*  amv   = (float*)wp;  wp += alup(szAmv) * CD;
  int*    tab   = (int*)wp;    wp += alup(szTab);
  bf16_t* part  = (bf16_t*)score;   // CD compact 16MiB part slots inside score region

  // slot strides in ELEMENTS (alup is identity here: all sizes are 256-multiples)
  const size_t SCS  = szSc / 4;                 // score slot stride (f32) = NPIX*4096
  const size_t ATTS = szAtt / 2;                // att slot stride (bf16) = NPIX*4096
  const size_t QKS  = (size_t)NPIX * KQ;
  const size_t VBS  = (size_t)NPV * 4096;
  const size_t PARTSLOT = (size_t)2 * 4096 * 1024;  // bf16 elems (split-K=2); 16MiB/slot

  build_tab<<<dim3(4), dim3(256), 0, stream>>>(tab);

  for (int g0 = 0; g0 < 8; g0 += G) {
    const float* boG = s + (size_t)g0 * 64 * HW_;
    const float* dgG = g + (size_t)g0 * 64 * HW_;

    conv1x1_3<<<dim3(384, G), dim3(256), 0, stream>>>(boG, dgG, g_w, g_b, t_w, t_b,
                                                      p_w, p_b, b1, b2, b3);
    unfold_qk<<<dim3(1, 2048, 2 * G), dim3(256), 0, stream>>>(b1, b3, qbuf, kbuf, tab);
    unfold_v <<<dim3(4, NPV, G),      dim3(256), 0, stream>>>(b2, vbufp, tab);

    for (int lb = 0; lb < G; lb += CD) {
      int cd = (G - lb >= CD) ? CD : 1;
      fp16_t* qb = qbuf + (size_t)lb * QKS;
      fp16_t* kb = kbuf + (size_t)lb * QKS;
      bf16_t* vb = vbufp + (size_t)lb * VBS;
      const float* bo = s + (size_t)(g0 + lb) * 64 * HW_;
      float* ob = out + (size_t)(g0 + lb) * 64 * HW_;

      // score[bat] = 10 * q[bat] k[bat]^T   (fp16, K=832, T=13)
      gemm256<fp16_t, float><<<dim3(256 * cd), dim3(512), 0, stream>>>(
          qb, KQ, kb, KQ, score, 4096,
          16, 256, (size_t)0, KQ, 0, 10.0f,
          1, QKS, QKS, SCS);
      softmax_rows<<<dim3(4096, cd), dim3(256), 0, stream>>>(score, att);
      // part[bat][spl] = att[bat][:, spl*2048+...] @ v[bat]^T  (split-K=2, T=32, bf16)
      gemm256<bf16_t, bf16_t><<<dim3(128 * cd), dim3(512), 0, stream>>>(
          att, 4096, vb, 4096, part, 1024,
          4, 64, (size_t)4096 * 1024, 2048, 2048, 1.0f,
          2, ATTS, VBS, PARTSLOT);
      reduce2<<<dim3(2048, cd), dim3(256), 0, stream>>>(part, amv);
      fold_norm<<<dim3(4096, cd), dim3(256), 0, stream>>>(amv, zi);
      out_conv<<<dim3(256, cd), dim3(256), 0, stream>>>(zi, bo, w_w, w_b, ob);
    }
  }
}

// Round 22
// 1347.496 us; speedup vs baseline: 1.1236x; 1.0063x over previous
//
#include <hip/hip_runtime.h>
#include <cstdint>
#include <cstddef>

// ---------------- types ----------------
typedef __bf16 bf16_t;
typedef _Float16 fp16_t;
typedef bf16_t bf16x8 __attribute__((ext_vector_type(8)));
typedef fp16_t fp16x8 __attribute__((ext_vector_type(8)));
typedef bf16_t bf16x2 __attribute__((ext_vector_type(2)));
typedef fp16_t fp16x2 __attribute__((ext_vector_type(2)));
typedef float  f32x4  __attribute__((ext_vector_type(4)));
typedef float  f32x2  __attribute__((ext_vector_type(2)));

#define GAS __attribute__((address_space(1)))
#define LAS __attribute__((address_space(3)))

__device__ __forceinline__ void g2l16(const void* g, void* l) {
  // async global->LDS, 16B per lane; LDS dest is wave-uniform base + lane*16
  __builtin_amdgcn_global_load_lds((const GAS unsigned int*)g,
                                   (LAS unsigned int*)l, 16, 0, 0);
}

__device__ __forceinline__ f32x4 mfma16(bf16x8 a, bf16x8 b, f32x4 c) {
  return __builtin_amdgcn_mfma_f32_16x16x32_bf16(a, b, c, 0, 0, 0);
}
__device__ __forceinline__ f32x4 mfma16(fp16x8 a, fp16x8 b, f32x4 c) {
  return __builtin_amdgcn_mfma_f32_16x16x32_f16(a, b, c, 0, 0, 0);
}
template <typename T> struct vec8;
template <> struct vec8<bf16_t> { using t = bf16x8; };
template <> struct vec8<fp16_t> { using t = fp16x8; };

// Problem constants
#define HW_  65536      // 256*256
#define NPIX 4096       // 64*64 patch grid
#define KQ   832        // 784 real + pad to 832 (fp16 single-pass), 832 % 64 == 0
#define NPV  1024       // v rows padded to 1024 (784 real)

// ------- decode table: tab[kk] = (c*HW+(ki-1)*256+(kj-1)+257) | ki<<20 | kj<<24 | 1<<28 ----
__global__ void build_tab(int* __restrict__ tab) {
  int kk = blockIdx.x * 256 + threadIdx.x;
  int v = 0;
  if (kk < 784) {
    int c = kk / 49, r = kk - c * 49, ki = r / 7, kj = r - ki * 7;
    int off = c * HW_ + (ki - 1) * 256 + (kj - 1) + 257;   // biased, >=0, <2^20
    v = off | (ki << 20) | (kj << 24) | (1 << 28);
  }
  tab[kk] = v;
}

// ------- 1x1 convs, dg read ONCE: z = blockIdx.x&1 (0: b1<-bo unroll8; 1: b2+b3<-dg unroll4)
// z=1 computes BOTH dg-derived outputs from one load stream: 32 f32x2 accums (64 VGPR) +
// 4 float2 loads in flight (~85 VGPR total). Tripwires: WRITE_SIZE ~49MB (no spill),
// VGPR >= ~80 (not pinned at 48 = round-16 mangle mode).
__global__ __launch_bounds__(256) void conv1x1_3(
    const float* __restrict__ bo, const float* __restrict__ dg,
    const float* __restrict__ gw, const float* __restrict__ gb,
    const float* __restrict__ tw, const float* __restrict__ tb,
    const float* __restrict__ pw, const float* __restrict__ pb,
    fp16_t* __restrict__ b1, bf16_t* __restrict__ b2, fp16_t* __restrict__ b3)
{
  __shared__ float wA[1024], wB[1024], bia[32];
  int tid  = threadIdx.x;
  int lb   = blockIdx.y;
  int z    = blockIdx.x & 1;
  int xblk = blockIdx.x >> 1;
  size_t hw = ((size_t)xblk * 256 + tid) * 2;

  if (z == 0) {
    // ---- b1 = gw*bo + gb (fp16), round-17 unroll-8 body ----
    const float* src = bo + (size_t)lb * 64 * HW_;
    for (int i = tid; i < 1024; i += 256) wA[i] = gw[i];
    if (tid < 16) bia[tid] = gb[tid];
    __syncthreads();
    f32x2 acc[16];
#pragma unroll
    for (int o = 0; o < 16; ++o) {
      float bv = bia[o];
      acc[o] = f32x2{bv, bv};
    }
    for (int c = 0; c < 64; c += 8) {
      float2 v[8];
#pragma unroll
      for (int u = 0; u < 8; ++u)
        v[u] = *(const float2*)(src + (size_t)(c + u) * HW_ + hw);
#pragma unroll
      for (int u = 0; u < 8; ++u)
#pragma unroll
        for (int o = 0; o < 16; ++o) {
          float wv = wA[o * 64 + c + u];
          acc[o][0] = fmaf(wv, v[u].x, acc[o][0]);
          acc[o][1] = fmaf(wv, v[u].y, acc[o][1]);
        }
    }
    fp16_t* dst = b1 + (size_t)lb * 16 * HW_;
#pragma unroll
    for (int o = 0; o < 16; ++o) {
      fp16x2 pk;
      pk[0] = (fp16_t)acc[o][0];
      pk[1] = (fp16_t)acc[o][1];
      *(fp16x2*)(dst + (size_t)o * HW_ + hw) = pk;
    }
  } else {
    // ---- b2 = tw*dg + tb (bf16) AND b3 = pw*dg + pb (fp16), one dg read, unroll-4 ----
    const float* src = dg + (size_t)lb * 64 * HW_;
    for (int i = tid; i < 1024; i += 256) { wA[i] = tw[i]; wB[i] = pw[i]; }
    if (tid < 16) { bia[tid] = tb[tid]; bia[16 + tid] = pb[tid]; }
    __syncthreads();
    f32x2 a2[16], a3[16];
#pragma unroll
    for (int o = 0; o < 16; ++o) {
      float v2 = bia[o], v3 = bia[16 + o];
      a2[o] = f32x2{v2, v2};
      a3[o] = f32x2{v3, v3};
    }
    for (int c = 0; c < 64; c += 4) {
      float2 v[4];
#pragma unroll
      for (int u = 0; u < 4; ++u)
        v[u] = *(const float2*)(src + (size_t)(c + u) * HW_ + hw);
#pragma unroll
      for (int u = 0; u < 4; ++u)
#pragma unroll
        for (int o = 0; o < 16; ++o) {
          float w2 = wA[o * 64 + c + u];
          float w3 = wB[o * 64 + c + u];
          a2[o][0] = fmaf(w2, v[u].x, a2[o][0]);
          a2[o][1] = fmaf(w2, v[u].y, a2[o][1]);
          a3[o][0] = fmaf(w3, v[u].x, a3[o][0]);
          a3[o][1] = fmaf(w3, v[u].y, a3[o][1]);
        }
    }
    bf16_t* d2 = b2 + (size_t)lb * 16 * HW_;
    fp16_t* d3 = b3 + (size_t)lb * 16 * HW_;
#pragma unroll
    for (int o = 0; o < 16; ++o) {
      bf16x2 p2;
      p2[0] = (bf16_t)a2[o][0];
      p2[1] = (bf16_t)a2[o][1];
      *(bf16x2*)(d2 + (size_t)o * HW_ + hw) = p2;
      fp16x2 p3;
      p3[0] = (fp16_t)a3[o][0];
      p3[1] = (fp16_t)a3[o][1];
      *(fp16x2*)(d3 + (size_t)o * HW_ + hw) = p3;
    }
  }
}

// ------- unfold q & k, table-driven, 8 gathers in flight ----------------------------------
__global__ __launch_bounds__(256) void unfold_qk(const fp16_t* __restrict__ b1,
                                                 const fp16_t* __restrict__ b3,
                                                 fp16_t* __restrict__ qb,
                                                 fp16_t* __restrict__ kb,
                                                 const int* __restrict__ tab)
{
  int tid = threadIdx.x;
  int lb = blockIdx.z >> 1, sel = blockIdx.z & 1;
  const fp16_t* src = (sel ? b3 : b1) + (size_t)lb * 16 * HW_;
  fp16_t* dst       = (sel ? kb : qb) + (size_t)lb * NPIX * KQ;
  int i0 = blockIdx.y, i1 = i0 + 2048;
  int oy0 = i0 >> 6, ox0 = i0 & 63;
  int oy1 = i1 >> 6, ox1 = i1 & 63;
  int pb0 = oy0 * 1024 + ox0 * 4;
  int pb1 = oy1 * 1024 + ox1 * 4;
  int t[4];
#pragma unroll
  for (int u = 0; u < 4; ++u) t[u] = tab[tid + u * 256];
  fp16_t v0[4], v1[4];
#pragma unroll
  for (int u = 0; u < 4; ++u) {
    int off = (t[u] & 0xFFFFF) - 257;
    int ki  = (t[u] >> 20) & 15;
    int kj  = (t[u] >> 24) & 15;
    int vld = t[u] >> 28;
    int y0 = oy0 * 4 + ki - 1, x0 = ox0 * 4 + kj - 1;
    int y1 = oy1 * 4 + ki - 1, x1 = ox1 * 4 + kj - 1;
    v0[u] = (vld && (unsigned)y0 < 256u && (unsigned)x0 < 256u)
            ? src[pb0 + off] : (fp16_t)0.f;
    v1[u] = (vld && (unsigned)y1 < 256u && (unsigned)x1 < 256u)
            ? src[pb1 + off] : (fp16_t)0.f;
  }
#pragma unroll
  for (int u = 0; u < 4; ++u) {
    int kk = tid + u * 256;
    if (kk < KQ) {
      dst[(size_t)i0 * KQ + kk] = v0[u];
      dst[(size_t)i1 * KQ + kk] = v1[u];
    }
  }
}

// ------- v unfold, table-driven (wave-uniform row decode), 4 gathers in flight -------------
__global__ __launch_bounds__(256) void unfold_v(const bf16_t* __restrict__ src,
                                                bf16_t* __restrict__ vb,
                                                const int* __restrict__ tab)
{
  int tid = threadIdx.x;
  int p  = blockIdx.y;
  int lb = blockIdx.z;
  src += (size_t)lb * 16 * HW_;
  vb  += (size_t)lb * NPV * 4096;
  int t = tab[p];                       // wave-uniform -> scalar load
  int off = (t & 0xFFFFF) - 257;
  int ki  = (t >> 20) & 15;
  int kj  = (t >> 24) & 15;
  int vld = t >> 28;
  int jb = blockIdx.x * 1024 + tid;
  bf16_t v[4];
#pragma unroll
  for (int u = 0; u < 4; ++u) {
    int j = jb + u * 256;
    int oy = j >> 6, ox = j & 63;
    int y = oy * 4 + ki - 1, x = ox * 4 + kj - 1;
    v[u] = (vld && (unsigned)y < 256u && (unsigned)x < 256u)
           ? src[oy * 1024 + ox * 4 + off] : (bf16_t)0.f;
  }
#pragma unroll
  for (int u = 0; u < 4; ++u)
    vb[(size_t)p * 4096 + jb + u * 256] = v[u];
}

// ---------------- 256x256-tile GEMM, 8-phase, batched: C = alpha*A*B^T ---------------------
// u = swz/bps -> (bat = u/nspl, spl = u%nspl); tile = swz%bps -> (bm,bn).
// REQUIRES: K % 64 == 0, T = K/64 >= 3; gridDim.x = nbat*nspl*bps.
template <typename T, typename OT>
__global__ __launch_bounds__(512, 2) void gemm256(
    const T* __restrict__ A, int lda,
    const T* __restrict__ B, int ldb,
    OT* __restrict__ C, int ldc,
    int nbn, int bps, size_t csplit, int K, int kofs, float alpha,
    int nspl, size_t abat, size_t bbat, size_t cbat)
{
  using v8t = typename vec8<T>::t;
  __shared__ __align__(16) T lds[8][8192];   // 8 half-slots x 16 KiB = 128 KiB

  int nwg = gridDim.x, wg = blockIdx.x;
  int swz = ((nwg & 7) == 0) ? ((wg & 7) * (nwg >> 3) + (wg >> 3)) : wg;
  int u   = swz / bps;
  int rem = swz - u * bps;
  int bat = u / nspl, spl = u - bat * nspl;
  int bm  = rem / nbn, bn = rem - bm * nbn;
  A += (size_t)bat * abat + (size_t)spl * (size_t)kofs;
  B += (size_t)bat * bbat + (size_t)spl * (size_t)kofs;
  C += (size_t)bat * cbat + (size_t)spl * csplit;

  int tid  = threadIdx.x;
  int lane = tid & 63;
  int wid  = tid >> 6;
  int wr   = wid >> 2, wc = wid & 3;        // wave -> 128-row x 64-col output block
  int l16  = lane & 15;

  const T* gA = A + (size_t)(bm * 256 + (tid & 255)) * lda + (tid >> 8) * 8;
  const T* gB = B + (size_t)(bn * 256 + (tid & 255)) * ldb + (tid >> 8) * 8;

#define STAGE(gsrc, koffe, slot) {                                   \
    const T* _s = (gsrc) + (koffe);                                  \
    g2l16(_s,      &lds[slot][(size_t)tid * 8]);                     \
    g2l16(_s + 16, &lds[slot][(size_t)(512 + tid) * 8]); }

  int aoff = ((lane >> 4) * 256 + wr * 128 + l16) * 8;
  int boff = ((lane >> 4) * 256 + wc * 64 + l16) * 8;

  f32x4 acc[8][4];
#pragma unroll
  for (int f = 0; f < 8; ++f)
#pragma unroll
    for (int q = 0; q < 4; ++q) acc[f][q] = f32x4{0.f, 0.f, 0.f, 0.f};

  int T_ = K >> 6;   // BK = 64

  // prologue: 7 halves in steady-state order
  STAGE(gB, 0, 1)        // Bk0(0)
  STAGE(gA, 0, 0)        // Ak0(0)
  STAGE(gB, 32, 3)       // Bk1(0)
  STAGE(gA, 32, 2)       // Ak1(0)
  STAGE(gB, 64, 5)       // Bk0(1)
  STAGE(gA, 64, 4)       // Ak0(1)
  STAGE(gB, 96, 7)       // Bk1(1)
  asm volatile("s_waitcnt vmcnt(6)" ::: "memory");   // tile 0 fully resident
  __builtin_amdgcn_s_barrier();

  for (int t = 0; t < T_; ++t) {
    int pi = (t & 1) * 4;          // current tile's slot base
    int po = ((t + 1) & 1) * 4;    // other parity
    const T* sAk0 = &lds[pi + 0][0];
    const T* sBk0 = &lds[pi + 1][0];
    const T* sAk1 = &lds[pi + 2][0];
    const T* sBk1 = &lds[pi + 3][0];
    v8t bg[4], af[4];

    // ---- phase 0: read B(ks0) + A(ks0, rf0-3) | stage Ak1(t+1) | MFMA q0 ----
#pragma unroll
    for (int q = 0; q < 4; ++q) bg[q] = *(const v8t*)(sBk0 + boff + q * 128);
#pragma unroll
    for (int f = 0; f < 4; ++f) af[f] = *(const v8t*)(sAk0 + aoff + f * 128);
    if (t + 1 < T_) STAGE(gA, (t + 1) * 64 + 32, po + 2)
    __builtin_amdgcn_s_barrier();
    asm volatile("s_waitcnt lgkmcnt(0)" ::: "memory");
    __builtin_amdgcn_sched_barrier(0);
    __builtin_amdgcn_s_setprio(1);
#pragma unroll
    for (int f = 0; f < 4; ++f)
#pragma unroll
      for (int q = 0; q < 4; ++q)
        acc[f][q] = mfma16(af[f], bg[q], acc[f][q]);
    __builtin_amdgcn_s_setprio(0);
    __builtin_amdgcn_s_barrier();

    // ---- phase 1: read A(ks0, rf4-7) | stage Bk0(t+2) | MFMA q1 ----
#pragma unroll
    for (int f = 0; f < 4; ++f) af[f] = *(const v8t*)(sAk0 + aoff + 512 + f * 128);
    if (t + 2 < T_) STAGE(gB, (t + 2) * 64, pi + 1)
    __builtin_amdgcn_s_barrier();
    asm volatile("s_waitcnt lgkmcnt(0)" ::: "memory");
    __builtin_amdgcn_sched_barrier(0);
    __builtin_amdgcn_s_setprio(1);
#pragma unroll
    for (int f = 0; f < 4; ++f)
#pragma unroll
      for (int q = 0; q < 4; ++q)
        acc[4 + f][q] = mfma16(af[f], bg[q], acc[4 + f][q]);
    __builtin_amdgcn_s_setprio(0);
    __builtin_amdgcn_s_barrier();

    // ---- phase 2: read B(ks1) + A(ks1, rf0-3) | stage Ak0(t+2) | MFMA q2 ----
#pragma unroll
    for (int q = 0; q < 4; ++q) bg[q] = *(const v8t*)(sBk1 + boff + q * 128);
#pragma unroll
    for (int f = 0; f < 4; ++f) af[f] = *(const v8t*)(sAk1 + aoff + f * 128);
    if (t + 2 < T_) STAGE(gA, (t + 2) * 64, pi + 0)
    __builtin_amdgcn_s_barrier();
    asm volatile("s_waitcnt lgkmcnt(0)" ::: "memory");
    __builtin_amdgcn_sched_barrier(0);
    __builtin_amdgcn_s_setprio(1);
#pragma unroll
    for (int f = 0; f < 4; ++f)
#pragma unroll
      for (int q = 0; q < 4; ++q)
        acc[f][q] = mfma16(af[f], bg[q], acc[f][q]);
    __builtin_amdgcn_s_setprio(0);
    __builtin_amdgcn_s_barrier();

    // ---- phase 3: read A(ks1, rf4-7) | stage Bk1(t+2) | MFMA q3 | boundary vmcnt ----
#pragma unroll
    for (int f = 0; f < 4; ++f) af[f] = *(const v8t*)(sAk1 + aoff + 512 + f * 128);
    if (t + 2 < T_) STAGE(gB, (t + 2) * 64 + 32, pi + 3)
    __builtin_amdgcn_s_barrier();
    asm volatile("s_waitcnt lgkmcnt(0)" ::: "memory");
    __builtin_amdgcn_sched_barrier(0);
    __builtin_amdgcn_s_setprio(1);
#pragma unroll
    for (int f = 0; f < 4; ++f)
#pragma unroll
      for (int q = 0; q < 4; ++q)
        acc[4 + f][q] = mfma16(af[f], bg[q], acc[4 + f][q]);
    __builtin_amdgcn_s_setprio(0);
    if (t < T_ - 2)       { asm volatile("s_waitcnt vmcnt(6)" ::: "memory"); }
    else if (t == T_ - 2) { asm volatile("s_waitcnt vmcnt(0)" ::: "memory"); }
    __builtin_amdgcn_s_barrier();
  }
#undef STAGE

  // C/D layout: col = lane&15, row = (lane>>4)*4 + reg ; frag rows = wr*128 + F*16
  int r0 = bm * 256 + wr * 128 + (lane >> 4) * 4;
  int c0 = bn * 256 + wc * 64 + l16;
#pragma unroll
  for (int f = 0; f < 8; ++f)
#pragma unroll
    for (int q = 0; q < 4; ++q) {
      OT* cp = C + (size_t)(r0 + f * 16) * ldc + c0 + q * 16;
#pragma unroll
      for (int r = 0; r < 4; ++r) cp[(size_t)r * ldc] = (OT)(alpha * acc[f][q][r]);
    }
}

// ---------------- fused row softmax (batched over blockIdx.y) ----------------
__global__ __launch_bounds__(256) void softmax_rows(const float* __restrict__ S,
                                                    bf16_t* __restrict__ Att)
{
  S   += (size_t)blockIdx.y * NPIX * 4096;
  Att += (size_t)blockIdx.y * NPIX * 4096;
  int row = blockIdx.x;
  int tid = threadIdx.x;
  int lane = tid & 63, wid = tid >> 6;
  const float4* Sp = (const float4*)(S + (size_t)row * 4096);
  float4 vv[4];
  float m = -3.4e38f;
#pragma unroll
  for (int u = 0; u < 4; ++u) {
    vv[u] = Sp[u * 256 + tid];
    m = fmaxf(m, fmaxf(fmaxf(vv[u].x, vv[u].y), fmaxf(vv[u].z, vv[u].w)));
  }
#pragma unroll
  for (int off = 32; off; off >>= 1) m = fmaxf(m, __shfl_xor(m, off));
  __shared__ float redm[4], reds[4];
  if (lane == 0) redm[wid] = m;
  __syncthreads();
  m = fmaxf(fmaxf(redm[0], redm[1]), fmaxf(redm[2], redm[3]));
  float ssum = 0.f;
#pragma unroll
  for (int u = 0; u < 4; ++u) {
    vv[u].x = __expf(vv[u].x - m); vv[u].y = __expf(vv[u].y - m);
    vv[u].z = __expf(vv[u].z - m); vv[u].w = __expf(vv[u].w - m);
    ssum += vv[u].x + vv[u].y + vv[u].z + vv[u].w;
  }
#pragma unroll
  for (int off = 32; off; off >>= 1) ssum += __shfl_xor(ssum, off);
  if (lane == 0) reds[wid] = ssum;
  __syncthreads();
  float inv = 1.0f / (reds[0] + reds[1] + reds[2] + reds[3]);
  ushort4* Ap = (ushort4*)(Att + (size_t)row * 4096);
#pragma unroll
  for (int u = 0; u < 4; ++u) {
    union { bf16_t b[4]; ushort4 q; } pk;
    pk.b[0] = (bf16_t)(vv[u].x * inv);
    pk.b[1] = (bf16_t)(vv[u].y * inv);
    pk.b[2] = (bf16_t)(vv[u].z * inv);
    pk.b[3] = (bf16_t)(vv[u].w * inv);
    Ap[u * 256 + tid] = pk.q;
  }
}

// ---------------- split-K=2 reduce (batched over blockIdx.y; slot stride 2*4096*1024) ------
__global__ __launch_bounds__(256) void reduce2(const bf16_t* __restrict__ part,
                                               float* __restrict__ amv)
{
  part += (size_t)blockIdx.y * 2 * 4096 * 1024;   // matches gemm2 cbat exactly
  amv  += (size_t)blockIdx.y * 4096 * 1024;
  size_t i = ((size_t)blockIdx.x * 256 + threadIdx.x) * 8;   // over 4096*1024 elems
  const size_t S = (size_t)4096 * 1024;
  bf16x8 a = *(const bf16x8*)(part + i);
  bf16x8 b = *(const bf16x8*)(part + i + S);
  float o[8];
#pragma unroll
  for (int j = 0; j < 8; ++j)
    o[j] = (float)a[j] + (float)b[j];
  float4* op = (float4*)(amv + i);
  op[0] = float4{o[0], o[1], o[2], o[3]};
  op[1] = float4{o[4], o[5], o[6], o[7]};
}

// ---------------- fold + mask normalize (batched over blockIdx.y) ----------------
__global__ __launch_bounds__(256) void fold_norm(const float* __restrict__ amv,
                                                 float* __restrict__ zi)
{
  amv += (size_t)blockIdx.y * 4096 * 1024;
  zi  += (size_t)blockIdx.y * 16 * HW_;
  int idx = blockIdx.x * 256 + threadIdx.x;   // c*65536 + h*256 + w
  int c = idx >> 16;
  int h = (idx >> 8) & 255;
  int w = idx & 255;
  int t = h + 3, u = w + 3;
  int oy0 = (t - 3) >> 2, oy1 = min(63, t >> 2);
  int ox0 = (u - 3) >> 2, ox1 = min(63, u >> 2);
  float sum = 0.f;
  for (int oy = oy0; oy <= oy1; ++oy) {
    int ki = t - oy * 4;
    for (int ox = ox0; ox <= ox1; ++ox) {
      int kj = u - ox * 4;
      sum += amv[(size_t)(oy * 64 + ox) * NPV + c * 49 + ki * 7 + kj];
    }
  }
  int cnt = (oy1 - oy0 + 1) * (ox1 - ox0 + 1);
  zi[idx] = sum / (float)cnt;
}

// ---------------- final conv (batched over blockIdx.y) ----------------
__global__ __launch_bounds__(256) void out_conv(const float* __restrict__ zi,
                                                const float* __restrict__ bo,
                                                const float* __restrict__ ww,
                                                const float* __restrict__ wb,
                                                float* __restrict__ outb)
{
  zi   += (size_t)blockIdx.y * 16 * HW_;
  bo   += (size_t)blockIdx.y * 64 * HW_;
  outb += (size_t)blockIdx.y * 64 * HW_;
  __shared__ float wws[1024], wbs[64];
  int tid = threadIdx.x;
  for (int i = tid; i < 1024; i += 256) wws[i] = ww[i];
  if (tid < 64) wbs[tid] = wb[tid];
  __syncthreads();
  int hw = blockIdx.x * 256 + tid;
  float z[16];
#pragma unroll
  for (int c = 0; c < 16; ++c) z[c] = zi[(size_t)c * HW_ + hw];
  for (int o = 0; o < 64; ++o) {
    float a = wbs[o];
#pragma unroll
    for (int c = 0; c < 16; ++c) a = fmaf(wws[o * 16 + c], z[c], a);
    outb[(size_t)o * HW_ + hw] = bo[(size_t)o * HW_ + hw] + a;
  }
}

// ---------------- host orchestration ----------------
static inline size_t alup(size_t x) { return (x + 255) & ~(size_t)255; }

extern "C" void kernel_launch(void* const* d_in, const int* in_sizes, int n_in,
                              void* d_out, int out_size, void* d_ws, size_t ws_size,
                              hipStream_t stream) {
  const float* s   = (const float*)d_in[0];
  const float* g   = (const float*)d_in[1];
  const float* g_w = (const float*)d_in[2];
  const float* g_b = (const float*)d_in[3];
  const float* t_w = (const float*)d_in[4];
  const float* t_b = (const float*)d_in[5];
  const float* p_w = (const float*)d_in[6];
  const float* p_b = (const float*)d_in[7];
  const float* w_w = (const float*)d_in[8];
  const float* w_b = (const float*)d_in[9];
  float* out = (float*)d_out;

  const size_t szB1 = (size_t)16 * HW_ * 2;          // fp16/bf16 conv outs (per batch)
  const size_t szQK = (size_t)NPIX * KQ * 2;         // per batch
  const size_t szV  = (size_t)NPV * 4096 * 2;        // per batch
  const size_t szSc = (size_t)NPIX * 4096 * 4;       // per chain slot (f32); part aliases
  const size_t szAtt = (size_t)NPIX * 4096 * 2;
  const size_t szZi  = (size_t)16 * HW_ * 4;
  const size_t szAmv = (size_t)NPIX * NPV * 4;
  const size_t szTab = (size_t)1024 * 4;

  // choose largest G in {8,4,2,1}; chain depth CD = 2 when G >= 2
  int G = 1;
  for (int cand = 8; cand >= 1; cand >>= 1) {
    int cd = cand >= 2 ? 2 : 1;
    size_t need = alup(szB1) * 3 * cand + alup(szQK) * 2 * cand + alup(szV) * cand
                + (size_t)cd * (alup(szSc) + alup(szAtt) + alup(szZi) + alup(szAmv))
                + alup(szTab);
    if (need <= ws_size) { G = cand; break; }
  }
  int CD = G >= 2 ? 2 : 1;

  uint8_t* wp = (uint8_t*)d_ws;
  fp16_t* b1    = (fp16_t*)wp; wp += alup(szB1) * G;
  bf16_t* b2    = (bf16_t*)wp; wp += alup(szB1) * G;
  fp16_t* b3    = (fp16_t*)wp; wp += alup(szB1) * G;
  fp16_t* qbuf  = (fp16_t*)wp; wp += alup(szQK) * G;
  fp16_t* kbuf  = (fp16_t*)wp; wp += alup(szQK) * G;
  bf16_t* vbufp = (bf16_t*)wp; wp += alup(szV) * G;
  float*  score = (float*)wp;  wp += alup(szSc) * CD;   // contiguous CD slots
  bf16_t* att   = (bf16_t*)wp; wp += alup(szAtt) * CD;
  float*  zi    = (float*)wp;  wp += alup(szZi) * CD;
  float*  amv   = (float*)wp;  wp += alup(szAmv) * CD;
  int*    tab   = (int*)wp;    wp += alup(szTab);
  bf16_t* part  = (bf16_t*)score;   // CD compact 16MiB part slots inside score region

  // slot strides in ELEMENTS (alup is identity here: all sizes are 256-multiples)
  const size_t SCS  = szSc / 4;                 // score slot stride (f32) = NPIX*4096
  const size_t ATTS = szAtt / 2;                // att slot stride (bf16) = NPIX*4096
  const size_t QKS  = (size_t)NPIX * KQ;
  const size_t VBS  = (size_t)NPV * 4096;
  const size_t PARTSLOT = (size_t)2 * 4096 * 1024;  // bf16 elems (split-K=2); 16MiB/slot

  build_tab<<<dim3(4), dim3(256), 0, stream>>>(tab);

  for (int g0 = 0; g0 < 8; g0 += G) {
    const float* boG = s + (size_t)g0 * 64 * HW_;
    const float* dgG = g + (size_t)g0 * 64 * HW_;

    conv1x1_3<<<dim3(256, G), dim3(256), 0, stream>>>(boG, dgG, g_w, g_b, t_w, t_b,
                                                      p_w, p_b, b1, b2, b3);
    unfold_qk<<<dim3(1, 2048, 2 * G), dim3(256), 0, stream>>>(b1, b3, qbuf, kbuf, tab);
    unfold_v <<<dim3(4, NPV, G),      dim3(256), 0, stream>>>(b2, vbufp, tab);

    for (int lb = 0; lb < G; lb += CD) {
      int cd = (G - lb >= CD) ? CD : 1;
      fp16_t* qb = qbuf + (size_t)lb * QKS;
      fp16_t* kb = kbuf + (size_t)lb * QKS;
      bf16_t* vb = vbufp + (size_t)lb * VBS;
      const float* bo = s + (size_t)(g0 + lb) * 64 * HW_;
      float* ob = out + (size_t)(g0 + lb) * 64 * HW_;

      // score[bat] = 10 * q[bat] k[bat]^T   (fp16, K=832, T=13)
      gemm256<fp16_t, float><<<dim3(256 * cd), dim3(512), 0, stream>>>(
          qb, KQ, kb, KQ, score, 4096,
          16, 256, (size_t)0, KQ, 0, 10.0f,
          1, QKS, QKS, SCS);
      softmax_rows<<<dim3(4096, cd), dim3(256), 0, stream>>>(score, att);
      // part[bat][spl] = att[bat][:, spl*2048+...] @ v[bat]^T  (split-K=2, T=32, bf16)
      gemm256<bf16_t, bf16_t><<<dim3(128 * cd), dim3(512), 0, stream>>>(
          att, 4096, vb, 4096, part, 1024,
          4, 64, (size_t)4096 * 1024, 2048, 2048, 1.0f,
          2, ATTS, VBS, PARTSLOT);
      reduce2<<<dim3(2048, cd), dim3(256), 0, stream>>>(part, amv);
      fold_norm<<<dim3(4096, cd), dim3(256), 0, stream>>>(amv, zi);
      out_conv<<<dim3(256, cd), dim3(256), 0, stream>>>(zi, bo, w_w, w_b, ob);
    }
  }
}